// Round 8
// baseline (823.499 us; speedup 1.0000x reference)
//
#include <hip/hip_runtime.h>
#include <hip/hip_bf16.h>

#define SCALE 0.17677669529663689f  // 32^-0.5

// ---------------- workspace offsets (in floats), total ~160 MB ----------------
#define OFF_S     0UL          // 16,777,216 (one half: 16 bh x 256 k x 4096 x)
#define OFF_XQT   16777216UL   // 4,194,304
#define OFF_XV    20971520UL   // 4,194,304
#define OFF_XKT   25165824UL   // 4,194,304
#define OFF_KQ    29360128UL   // 262,144
#define OFF_KK    29622272UL   // 262,144
#define OFF_KV    29884416UL   // 262,144
#define OFF_KATT  30146560UL   // 262,144
#define OFF_XATT  30408704UL   // 4,194,304
#define OFF_MT    34603008UL   // maskT 4 MB
#define OFF_MORI  35651584UL   // 8192 ints
#define OFF_OSUMP 35659776UL   // 2,097,152  [z][k][8 buckets][64 xblocks]
#define OFF_ACCP  37756928UL   // 2,097,152  [z][k][16 xs][32 d]
#define OFF_MLP   39854080UL   // 131,072    [z][k][16 xs] float2
#define OFF_FLAG  39985152UL

__device__ __forceinline__ float b2f(unsigned int u) {
    union { unsigned int i; float f; } v; v.i = u << 16; return v.f;
}

// ---------------- dtype detection ----------------
__global__ __launch_bounds__(256) void detect_kernel(
    const unsigned int* __restrict__ mask, const unsigned int* __restrict__ xf,
    int* __restrict__ flags)
{
    __shared__ unsigned int orv;
    __shared__ int cnt;
    int t = threadIdx.x;
    if (t == 0) { orv = 0u; cnt = 0; }
    __syncthreads();
    if (blockIdx.x == 0) {
        unsigned int v = 0;
        for (int i = t; i < 16384; i += 256) v |= mask[i];
        atomicOr(&orv, v);
        __syncthreads();
        if (t == 0) {
            unsigned int o = orv;
            int f;
            if (o <= 1u || o == 0x3F800000u) f = 0;
            else if (o & 0x00800080u)        f = 2;
            else                             f = 1;
            flags[0] = f;
        }
    } else {
        int c = 0;
        for (int i = t; i < 4096; i += 256) {
            unsigned int h = xf[i] & 0xFFFFu;
            unsigned int e = (h >> 7) & 0xFFu;
            if (h == 0u || (e >= 0x75u && e <= 0x82u)) c++;
        }
        atomicAdd(&cnt, c);
        __syncthreads();
        if (t == 0) flags[1] = (cnt > 3000) ? 1 : 0;
    }
}

// ---------------- qkv2: mode-0 GEMM, 128x128 tile, 8x8 microtile ----------------
// A(16384x256) @ W(256x768); q,k -> [bh][d][4096] transposed; v -> [bh][x][32]
__global__ __launch_bounds__(256) void qkv2_kernel(
    const void* __restrict__ A, const void* __restrict__ W,
    float* __restrict__ oq, float* __restrict__ ok, float* __restrict__ ov,
    const int* __restrict__ flags)
{
    __shared__ __align__(16) float As[16][136];
    __shared__ __align__(16) float Bs[16][128];
    int bf = flags[1];
    const float* A32 = (const float*)A;
    const float* W32 = (const float*)W;
    const unsigned short* A16 = (const unsigned short*)A;
    const unsigned short* W16 = (const unsigned short*)W;
    int m0 = blockIdx.x * 128;
    int n0 = blockIdx.y * 128;
    int id = threadIdx.x;
    int tm = id >> 4, tn = id & 15;
    float acc[8][8] = {};
    for (int k0 = 0; k0 < 256; k0 += 16) {
        int r = id >> 1, ck = (id & 1) * 8;
        int rk = id >> 4, cn = (id & 15) * 8;
        if (bf) {
            uint4 a4 = *(const uint4*)&A16[(size_t)(m0 + r) * 256 + k0 + ck];
            As[ck + 0][r] = b2f(a4.x & 0xFFFFu); As[ck + 1][r] = b2f(a4.x >> 16);
            As[ck + 2][r] = b2f(a4.y & 0xFFFFu); As[ck + 3][r] = b2f(a4.y >> 16);
            As[ck + 4][r] = b2f(a4.z & 0xFFFFu); As[ck + 5][r] = b2f(a4.z >> 16);
            As[ck + 6][r] = b2f(a4.w & 0xFFFFu); As[ck + 7][r] = b2f(a4.w >> 16);
            uint4 w4 = *(const uint4*)&W16[(size_t)(k0 + rk) * 768 + n0 + cn];
            Bs[rk][cn + 0] = b2f(w4.x & 0xFFFFu); Bs[rk][cn + 1] = b2f(w4.x >> 16);
            Bs[rk][cn + 2] = b2f(w4.y & 0xFFFFu); Bs[rk][cn + 3] = b2f(w4.y >> 16);
            Bs[rk][cn + 4] = b2f(w4.z & 0xFFFFu); Bs[rk][cn + 5] = b2f(w4.z >> 16);
            Bs[rk][cn + 6] = b2f(w4.w & 0xFFFFu); Bs[rk][cn + 7] = b2f(w4.w >> 16);
        } else {
            float4 a0 = *(const float4*)&A32[(size_t)(m0 + r) * 256 + k0 + ck];
            float4 a1 = *(const float4*)&A32[(size_t)(m0 + r) * 256 + k0 + ck + 4];
            As[ck + 0][r] = a0.x; As[ck + 1][r] = a0.y;
            As[ck + 2][r] = a0.z; As[ck + 3][r] = a0.w;
            As[ck + 4][r] = a1.x; As[ck + 5][r] = a1.y;
            As[ck + 6][r] = a1.z; As[ck + 7][r] = a1.w;
            *(float4*)&Bs[rk][cn]     = *(const float4*)&W32[(size_t)(k0 + rk) * 768 + n0 + cn];
            *(float4*)&Bs[rk][cn + 4] = *(const float4*)&W32[(size_t)(k0 + rk) * 768 + n0 + cn + 4];
        }
        __syncthreads();
        #pragma unroll
        for (int kk = 0; kk < 16; kk++) {
            float a[8], b[8];
            *(float4*)&a[0] = *(const float4*)&As[kk][tm * 8];
            *(float4*)&a[4] = *(const float4*)&As[kk][tm * 8 + 4];
            *(float4*)&b[0] = *(const float4*)&Bs[kk][tn * 8];
            *(float4*)&b[4] = *(const float4*)&Bs[kk][tn * 8 + 4];
            #pragma unroll
            for (int i = 0; i < 8; i++)
                #pragma unroll
                for (int j = 0; j < 8; j++)
                    acc[i][j] = fmaf(a[i], b[j], acc[i][j]);
        }
        __syncthreads();
    }
    int sec = n0 >> 8;
    int b = m0 >> 12;
    int rr0 = (m0 & 4095) + tm * 8;
    if (sec < 2) {
        float* dstb = (sec == 0) ? oq : ok;
        #pragma unroll
        for (int j = 0; j < 8; j++) {
            int col = n0 + tn * 8 + j;
            int hh = (col >> 5) & 7, d = col & 31;
            size_t base = (((size_t)(b * 8 + hh)) * 32 + d) * 4096 + rr0;
            *(float4*)&dstb[base]     = make_float4(acc[0][j], acc[1][j], acc[2][j], acc[3][j]);
            *(float4*)&dstb[base + 4] = make_float4(acc[4][j], acc[5][j], acc[6][j], acc[7][j]);
        }
    } else {
        int hh = ((n0 + tn * 8) >> 5) & 7, d0 = (n0 + tn * 8) & 31;
        #pragma unroll
        for (int i = 0; i < 8; i++) {
            size_t base = (((size_t)(b * 8 + hh)) * 4096 + rr0 + i) * 32 + d0;
            *(float4*)&ov[base]     = make_float4(acc[i][0], acc[i][1], acc[i][2], acc[i][3]);
            *(float4*)&ov[base + 4] = make_float4(acc[i][4], acc[i][5], acc[i][6], acc[i][7]);
        }
    }
}

// ---------------- qkv (mode-1, kernal): 64x64 tile ----------------
__global__ __launch_bounds__(256) void qkv_kernel(
    const void* __restrict__ A, const void* __restrict__ W,
    float* __restrict__ oq, float* __restrict__ ok, float* __restrict__ ov,
    const int* __restrict__ flags)
{
    __shared__ __align__(16) float As[16][68];
    __shared__ __align__(16) float Bs[16][64];
    int bf = flags[1];
    const float* A32 = (const float*)A;
    const float* W32 = (const float*)W;
    const unsigned short* A16 = (const unsigned short*)A;
    const unsigned short* W16 = (const unsigned short*)W;
    int m0 = blockIdx.x * 64;
    int n0 = blockIdx.y * 64;
    int id = threadIdx.x;
    int tm = id >> 4, tn = id & 15;
    float acc[4][4] = {};
    for (int k0 = 0; k0 < 256; k0 += 16) {
        int r = id >> 2, ck = (id & 3) * 4;
        int rk = id >> 4, cn = (id & 15) * 4;
        if (bf) {
            uint2 a2 = *(const uint2*)&A16[(size_t)(m0 + r) * 256 + k0 + ck];
            As[ck + 0][r] = b2f(a2.x & 0xFFFFu); As[ck + 1][r] = b2f(a2.x >> 16);
            As[ck + 2][r] = b2f(a2.y & 0xFFFFu); As[ck + 3][r] = b2f(a2.y >> 16);
            uint2 w2 = *(const uint2*)&W16[(size_t)(k0 + rk) * 768 + n0 + cn];
            Bs[rk][cn + 0] = b2f(w2.x & 0xFFFFu); Bs[rk][cn + 1] = b2f(w2.x >> 16);
            Bs[rk][cn + 2] = b2f(w2.y & 0xFFFFu); Bs[rk][cn + 3] = b2f(w2.y >> 16);
        } else {
            float4 a4 = *(const float4*)&A32[(size_t)(m0 + r) * 256 + k0 + ck];
            As[ck + 0][r] = a4.x; As[ck + 1][r] = a4.y;
            As[ck + 2][r] = a4.z; As[ck + 3][r] = a4.w;
            *(float4*)&Bs[rk][cn] = *(const float4*)&W32[(size_t)(k0 + rk) * 768 + n0 + cn];
        }
        __syncthreads();
        #pragma unroll
        for (int kk = 0; kk < 16; kk++) {
            float4 a = *(const float4*)&As[kk][tm * 4];
            float4 b = *(const float4*)&Bs[kk][tn * 4];
            float av[4] = {a.x, a.y, a.z, a.w};
            float bv[4] = {b.x, b.y, b.z, b.w};
            #pragma unroll
            for (int i = 0; i < 4; i++)
                #pragma unroll
                for (int j = 0; j < 4; j++)
                    acc[i][j] = fmaf(av[i], bv[j], acc[i][j]);
        }
        __syncthreads();
    }
    #pragma unroll
    for (int i = 0; i < 4; i++) {
        int row = m0 + tm * 4 + i;
        int b = row >> 8, rr = row & 255;
        #pragma unroll
        for (int j = 0; j < 4; j++) {
            int col = n0 + tn * 4 + j;
            int s2 = col >> 8, hh = (col >> 5) & 7, d = col & 31;
            float* dst = s2 == 0 ? oq : (s2 == 1 ? ok : ov);
            dst[(((size_t)(b * 8 + hh)) * 256 + rr) * 32 + d] = acc[i][j];
        }
    }
}

// ---------------- mask bit-packing ----------------
__global__ __launch_bounds__(256) void maskpack_kernel(
    const void* __restrict__ mask, unsigned int* __restrict__ maskT,
    const int* __restrict__ flags)
{
    int bh = blockIdx.x >> 7;
    int x0 = (blockIdx.x & 127) * 32;
    int t = threadIdx.x;
    int wv = t >> 6, lane = t & 63;
    int mode = flags[0];
    __shared__ unsigned int lds[32][8];
    for (int it = 0; it < 8; it++) {
        int xl = wv * 8 + it;
        size_t rb = ((size_t)bh * 4096 + x0 + xl) * 256;
        unsigned int nib;
        if (mode == 0) {
            uint4 m = ((const uint4*)((const unsigned int*)mask + rb))[lane];
            nib = (unsigned int)(m.x != 0u) | ((unsigned int)(m.y != 0u) << 1)
                | ((unsigned int)(m.z != 0u) << 2) | ((unsigned int)(m.w != 0u) << 3);
        } else if (mode == 1) {
            unsigned int m = ((const unsigned int*)mask)[rb / 4 + lane];
            nib = (unsigned int)((m & 0xFFu) != 0u) | ((unsigned int)((m & 0xFF00u) != 0u) << 1)
                | ((unsigned int)((m & 0xFF0000u) != 0u) << 2)
                | ((unsigned int)((m & 0xFF000000u) != 0u) << 3);
        } else {
            uint2 m = ((const uint2*)((const unsigned short*)mask + rb))[lane];
            nib = (unsigned int)((m.x & 0xFFFFu) != 0u) | ((unsigned int)((m.x >> 16) != 0u) << 1)
                | ((unsigned int)((m.y & 0xFFFFu) != 0u) << 2)
                | ((unsigned int)((m.y >> 16) != 0u) << 3);
        }
        unsigned long long b0 = __ballot((nib & 1u) != 0u);
        unsigned long long b1 = __ballot((nib & 2u) != 0u);
        unsigned long long b2 = __ballot((nib & 4u) != 0u);
        unsigned long long b3 = __ballot((nib & 8u) != 0u);
        if (lane < 8) {
            int j = lane >> 1;
            unsigned long long bb = j == 0 ? b0 : j == 1 ? b1 : j == 2 ? b2 : b3;
            lds[xl][lane] = (lane & 1) ? (unsigned int)(bb >> 32) : (unsigned int)bb;
        }
    }
    __syncthreads();
    int widx = (t & 3) * 2 + (t >> 7);
    int bitpos = (t >> 2) & 31;
    unsigned int w = 0u;
    #pragma unroll
    for (int xl = 0; xl < 32; xl++)
        w |= ((lds[xl][widx] >> bitpos) & 1u) << xl;
    maskT[((size_t)bh * 256 + t) * 128 + (x0 >> 5)] = w;
}

// ---------------- S1 GEMM + orientation-sum partials ----------------
// grid: (64 xtiles, 4 ktiles, 16 z)
__global__ __launch_bounds__(256) void s1_kernel(
    const float* __restrict__ kq, const float* __restrict__ xkT, float* __restrict__ S,
    const int* __restrict__ polar, float* __restrict__ osumP, int bo)
{
    __shared__ __align__(16) float Aq[32][68];
    __shared__ __align__(16) float Bs[32][64];
    __shared__ float osum_l[64][8];
    int z = blockIdx.z;
    size_t bhg = (size_t)(bo * 8 + z);
    int b = (int)(bhg >> 3);
    int k0 = blockIdx.y * 64;
    int x0 = blockIdx.x * 64;
    int id = threadIdx.x;
    ((float*)osum_l)[id] = 0.f;
    ((float*)osum_l)[id + 256] = 0.f;
    {
        int c4 = (id & 7) * 4;
        #pragma unroll
        for (int rep = 0; rep < 2; rep++) {
            int r = (id >> 3) + rep * 32;
            float4 a = *(const float4*)&kq[(bhg * 256 + k0 + r) * 32 + c4];
            Aq[c4 + 0][r] = a.x; Aq[c4 + 1][r] = a.y;
            Aq[c4 + 2][r] = a.z; Aq[c4 + 3][r] = a.w;
        }
    }
    {
        int c = (id & 15) * 4;
        #pragma unroll
        for (int rep = 0; rep < 2; rep++) {
            int r = (id >> 4) + rep * 16;
            *(float4*)&Bs[r][c] = *(const float4*)&xkT[(bhg * 32 + r) * 4096 + x0 + c];
        }
    }
    __syncthreads();
    int tm = id >> 4, tn = id & 15;
    float acc[4][4] = {};
    #pragma unroll
    for (int dd = 0; dd < 32; dd++) {
        float4 a = *(const float4*)&Aq[dd][tm * 4];
        float4 bb = *(const float4*)&Bs[dd][tn * 4];
        float av[4] = {a.x, a.y, a.z, a.w};
        float bv[4] = {bb.x, bb.y, bb.z, bb.w};
        #pragma unroll
        for (int i = 0; i < 4; i++)
            #pragma unroll
            for (int j = 0; j < 4; j++)
                acc[i][j] = fmaf(av[i], bv[j], acc[i][j]);
    }
    int xb = x0 + tn * 4;
    #pragma unroll
    for (int i = 0; i < 4; i++) {
        int row = tm * 4 + i;
        int k = k0 + row;
        float4 o;
        o.x = acc[i][0] * SCALE; o.y = acc[i][1] * SCALE;
        o.z = acc[i][2] * SCALE; o.w = acc[i][3] * SCALE;
        *(float4*)&S[((size_t)z * 256 + k) * 4096 + xb] = o;
        int4 p4 = *(const int4*)&polar[((size_t)b * 256 + k) * 4096 + xb];
        int pv[4] = {p4.x, p4.y, p4.z, p4.w};
        float sv[4] = {o.x, o.y, o.z, o.w};
        #pragma unroll
        for (int j = 0; j < 4; j++) {
            int pp = pv[j];
            pp = pp < 0 ? 0 : (pp > 7 ? 7 : pp);
            atomicAdd(&osum_l[row][pp], fabsf(sv[j]));
        }
    }
    __syncthreads();
    #pragma unroll
    for (int rep = 0; rep < 2; rep++) {
        int idx = id + rep * 256;
        int row = idx >> 3, o = idx & 7;
        osumP[(((size_t)z * 256 + k0 + row) * 8 + o) * 64 + blockIdx.x] = osum_l[row][o];
    }
}

// ---------------- argmax: osumP partial sums -> mori ----------------
// grid: 128 blocks x 256 (8 threads per k-row, 32 rows/block)
__global__ __launch_bounds__(256) void argmax_kernel(
    const float* __restrict__ osumP, int* __restrict__ mori, int bo)
{
    __shared__ float sums[32][8];
    int id = threadIdx.x;
    int row_l = id >> 3, o = id & 7;
    int gk = blockIdx.x * 32 + row_l;
    int z = gk >> 8, k = gk & 255;
    const float4* pp = (const float4*)&osumP[(((size_t)z * 256 + k) * 8 + o) * 64];
    float s = 0.f;
    #pragma unroll
    for (int i = 0; i < 16; i++) {
        float4 v = pp[i];
        s += v.x + v.y + v.z + v.w;
    }
    sums[row_l][o] = s;
    __syncthreads();
    if (id < 32) {
        int gk2 = blockIdx.x * 32 + id;
        int z2 = gk2 >> 8, k2 = gk2 & 255;
        float best = sums[id][0]; int bi = 0;
        #pragma unroll
        for (int o2 = 1; o2 < 8; o2++)
            if (sums[id][o2] > best) { best = sums[id][o2]; bi = o2; }
        mori[(size_t)(bo * 8 + z2) * 256 + k2] = bi;
    }
}

// ---------------- av1 online: bias+mask, online softmax over x, partials out ----
// grid: (16 xs, 4 ktiles, 16 z)
__global__ __launch_bounds__(256) void av1_kernel(
    const float* __restrict__ S, const float* __restrict__ xv,
    const int* __restrict__ rd, const int* __restrict__ polar,
    const unsigned int* __restrict__ maskT,
    const void* __restrict__ dis_emb, const void* __restrict__ polar_emb,
    const int* __restrict__ mori, const int* __restrict__ flags,
    float* __restrict__ accP, float2* __restrict__ mlP, int bo)
{
    __shared__ __align__(16) float At[64][68];
    __shared__ __align__(16) float Vt[64][32];
    __shared__ float disc[66];
    __shared__ float pem[8];
    __shared__ int mo_l[64];
    int z = blockIdx.z;
    int bhg = bo * 8 + z, b = bhg >> 3, h = bhg & 7;
    int k0 = blockIdx.y * 64;
    int xs = blockIdx.x;
    int id = threadIdx.x;
    int bf = flags[1];
    if (id < 66) disc[id] = bf ? b2f(((const unsigned short*)dis_emb)[id * 8 + h])
                               : ((const float*)dis_emb)[id * 8 + h];
    if (id < 8) pem[id] = bf ? b2f(((const unsigned short*)polar_emb)[id])
                             : ((const float*)polar_emb)[id];
    if (id < 64) mo_l[id] = mori[(size_t)bhg * 256 + k0 + id];
    __syncthreads();
    int r = id >> 2, p = id & 3;
    float acc[8] = {};
    float m = -3.0e38f, l = 0.f;
    for (int c8 = 0; c8 < 4; c8++) {
        int xc = xs * 256 + c8 * 64;
        if (c8) __syncthreads();
        {
            int c = (id & 15) * 4;
            #pragma unroll
            for (int rep = 0; rep < 4; rep++) {
                int rr = (id >> 4) + rep * 16;
                int kg = k0 + rr;
                float4 s4 = *(const float4*)&S[((size_t)z * 256 + kg) * 4096 + xc + c];
                size_t rib = ((size_t)b * 256 + kg) * 4096 + xc + c;
                int4 r4 = *(const int4*)&rd[rib];
                int4 p4 = *(const int4*)&polar[rib];
                unsigned int mw = maskT[((size_t)bhg * 256 + kg) * 128 + ((xc + c) >> 5)];
                int mo = mo_l[rr];
                float sv[4] = {s4.x, s4.y, s4.z, s4.w};
                int rv[4] = {r4.x, r4.y, r4.z, r4.w};
                int pv[4] = {p4.x, p4.y, p4.z, p4.w};
                float e[4];
                #pragma unroll
                for (int j = 0; j < 4; j++) {
                    int pp = pv[j];
                    pp = pp < 0 ? 0 : (pp > 7 ? 7 : pp);
                    float bias = disc[rv[j]] + pem[(pp - mo + 8) & 7];
                    e[j] = (((mw >> ((xc + c + j) & 31)) & 1u) ? -1e6f : sv[j]) + bias;
                }
                *(float4*)&At[rr][c] = make_float4(e[0], e[1], e[2], e[3]);
            }
        }
        {
            int c = (id & 7) * 4;
            #pragma unroll
            for (int rep = 0; rep < 2; rep++) {
                int rr = (id >> 3) + rep * 32;
                *(float4*)&Vt[rr][c] = *(const float4*)&xv[((size_t)bhg * 4096 + xc + rr) * 32 + c];
            }
        }
        __syncthreads();
        float mc = -3.0e38f;
        #pragma unroll
        for (int q4 = 0; q4 < 64; q4 += 4) {
            float4 v = *(const float4*)&At[r][q4];
            mc = fmaxf(mc, fmaxf(fmaxf(v.x, v.y), fmaxf(v.z, v.w)));
        }
        float mn = fmaxf(m, mc);
        float f = __expf(m - mn);
        m = mn;
        l *= f;
        #pragma unroll
        for (int j = 0; j < 8; j++) acc[j] *= f;
        #pragma unroll
        for (int q4 = 0; q4 < 64; q4 += 4) {
            float4 lv = *(const float4*)&At[r][q4];
            float le[4] = {lv.x, lv.y, lv.z, lv.w};
            #pragma unroll
            for (int u = 0; u < 4; u++) {
                float e = __expf(le[u] - m);
                l += e;
                float4 v0 = *(const float4*)&Vt[q4 + u][p * 8];
                float4 v1 = *(const float4*)&Vt[q4 + u][p * 8 + 4];
                acc[0] = fmaf(e, v0.x, acc[0]);
                acc[1] = fmaf(e, v0.y, acc[1]);
                acc[2] = fmaf(e, v0.z, acc[2]);
                acc[3] = fmaf(e, v0.w, acc[3]);
                acc[4] = fmaf(e, v1.x, acc[4]);
                acc[5] = fmaf(e, v1.y, acc[5]);
                acc[6] = fmaf(e, v1.z, acc[6]);
                acc[7] = fmaf(e, v1.w, acc[7]);
            }
        }
    }
    size_t pbase = (((size_t)z * 256 + k0 + r) * 16 + xs) * 32 + p * 8;
    *(float4*)&accP[pbase]     = make_float4(acc[0], acc[1], acc[2], acc[3]);
    *(float4*)&accP[pbase + 4] = make_float4(acc[4], acc[5], acc[6], acc[7]);
    if (p == 0) mlP[((size_t)z * 256 + k0 + r) * 16 + xs] = make_float2(m, l);
}

// ---------------- combine: merge 16 x-split partials -> k_att ----------------
// grid: (4 ktiles, 16 z), 256 threads (4 per k-row)
__global__ __launch_bounds__(256) void combine_kernel(
    const float* __restrict__ accP, const float2* __restrict__ mlP,
    float* __restrict__ k_att, int bo)
{
    int z = blockIdx.y;
    int bhg = bo * 8 + z, b = bhg >> 3, h = bhg & 7;
    int id = threadIdx.x;
    int r = id >> 2, p = id & 3;
    int k = blockIdx.x * 64 + r;
    float2 ml[16];
    float M = -3.0e38f;
    #pragma unroll
    for (int i = 0; i < 16; i++) {
        ml[i] = mlP[((size_t)z * 256 + k) * 16 + i];
        M = fmaxf(M, ml[i].x);
    }
    float L = 0.f;
    float w[16];
    #pragma unroll
    for (int i = 0; i < 16; i++) {
        w[i] = __expf(ml[i].x - M);
        L += ml[i].y * w[i];
    }
    float inv = 1.f / L;
    float acc[8] = {};
    #pragma unroll
    for (int i = 0; i < 16; i++) {
        size_t base = (((size_t)z * 256 + k) * 16 + i) * 32 + p * 8;
        float4 a0 = *(const float4*)&accP[base];
        float4 a1 = *(const float4*)&accP[base + 4];
        acc[0] = fmaf(w[i], a0.x, acc[0]);
        acc[1] = fmaf(w[i], a0.y, acc[1]);
        acc[2] = fmaf(w[i], a0.z, acc[2]);
        acc[3] = fmaf(w[i], a0.w, acc[3]);
        acc[4] = fmaf(w[i], a1.x, acc[4]);
        acc[5] = fmaf(w[i], a1.y, acc[5]);
        acc[6] = fmaf(w[i], a1.z, acc[6]);
        acc[7] = fmaf(w[i], a1.w, acc[7]);
    }
    float* dst = &k_att[((size_t)b * 256 + k) * 256 + h * 32 + p * 8];
    *(float4*)&dst[0] = make_float4(acc[0] * inv, acc[1] * inv, acc[2] * inv, acc[3] * inv);
    *(float4*)&dst[4] = make_float4(acc[4] * inv, acc[5] * inv, acc[6] * inv, acc[7] * inv);
}

// ---------------- fa2: fused QK+bias -> online softmax -> PV ----------------
__global__ __launch_bounds__(256) void fa2_kernel(
    const float* __restrict__ kk, const float* __restrict__ xqT, const float* __restrict__ kv,
    const int* __restrict__ rd, const int* __restrict__ polar,
    const unsigned int* __restrict__ maskT,
    const void* __restrict__ dis_emb, const void* __restrict__ polar_emb,
    const int* __restrict__ mori, const int* __restrict__ flags,
    float* __restrict__ x_att, int bo)
{
    __shared__ __align__(16) float Aq[32][34];
    __shared__ __align__(16) float Bs[32][64];
    __shared__ __align__(16) float At2[64][34];
    __shared__ __align__(16) float Vt[32][32];
    __shared__ float disc[66];
    __shared__ float pem[8];
    __shared__ int mo_l[256];
    int z = blockIdx.y;
    int bhg = bo * 8 + z, b = bhg >> 3, h = bhg & 7;
    int x0 = blockIdx.x * 64;
    int id = threadIdx.x;
    int bf = flags[1];
    if (id < 66) disc[id] = bf ? b2f(((const unsigned short*)dis_emb)[id * 8 + h])
                               : ((const float*)dis_emb)[id * 8 + h];
    if (id < 8) pem[id] = bf ? b2f(((const unsigned short*)polar_emb)[id])
                             : ((const float*)polar_emb)[id];
    mo_l[id] = mori[(size_t)bhg * 256 + id];
    {
        int c = (id & 15) * 4;
        #pragma unroll
        for (int rep = 0; rep < 2; rep++) {
            int r = (id >> 4) + rep * 16;
            *(float4*)&Bs[r][c] = *(const float4*)&xqT[((size_t)bhg * 32 + r) * 4096 + x0 + c];
        }
    }
    int tm = id >> 4, tn = id & 15;
    int xr = id >> 2, p = id & 3;
    float acc8[8] = {};
    float m = -3.0e38f, l = 0.f;
    for (int kc = 0; kc < 256; kc += 32) {
        __syncthreads();
        {
            int r = id >> 3, c4 = (id & 7) * 4;
            float4 a = *(const float4*)&kk[((size_t)bhg * 256 + kc + r) * 32 + c4];
            Aq[c4 + 0][r] = a.x; Aq[c4 + 1][r] = a.y;
            Aq[c4 + 2][r] = a.z; Aq[c4 + 3][r] = a.w;
            *(float4*)&Vt[r][c4] = *(const float4*)&kv[((size_t)bhg * 256 + kc + r) * 32 + c4];
        }
        __syncthreads();
        float acc[2][4] = {};
        #pragma unroll
        for (int dd = 0; dd < 32; dd++) {
            float2 a2 = *(const float2*)&Aq[dd][tm * 2];
            float4 b4 = *(const float4*)&Bs[dd][tn * 4];
            float bv[4] = {b4.x, b4.y, b4.z, b4.w};
            #pragma unroll
            for (int j = 0; j < 4; j++) {
                acc[0][j] = fmaf(a2.x, bv[j], acc[0][j]);
                acc[1][j] = fmaf(a2.y, bv[j], acc[1][j]);
            }
        }
        int xb = x0 + tn * 4;
        #pragma unroll
        for (int i = 0; i < 2; i++) {
            int kl = tm * 2 + i;
            int k = kc + kl;
            int mo = mo_l[k];
            size_t rib = ((size_t)b * 256 + k) * 4096 + xb;
            int4 r4 = *(const int4*)&rd[rib];
            int4 p4 = *(const int4*)&polar[rib];
            unsigned int mw = maskT[((size_t)bhg * 256 + k) * 128 + (xb >> 5)];
            int rv[4] = {r4.x, r4.y, r4.z, r4.w};
            int pv[4] = {p4.x, p4.y, p4.z, p4.w};
            #pragma unroll
            for (int j = 0; j < 4; j++) {
                int pp = pv[j];
                pp = pp < 0 ? 0 : (pp > 7 ? 7 : pp);
                float bias = disc[rv[j]] + pem[(pp - mo + 8) & 7];
                float s = acc[i][j] * SCALE;
                At2[tn * 4 + j][kl] =
                    (((mw >> ((xb + j) & 31)) & 1u) ? -1e9f : s) + bias;
            }
        }
        __syncthreads();
        float mc = -3.0e38f;
        #pragma unroll
        for (int q4 = 0; q4 < 32; q4 += 4) {
            float4 v = *(const float4*)&At2[xr][q4];
            mc = fmaxf(mc, fmaxf(fmaxf(v.x, v.y), fmaxf(v.z, v.w)));
        }
        float mn = fmaxf(m, mc);
        float f = __expf(m - mn);
        m = mn;
        l *= f;
        #pragma unroll
        for (int j = 0; j < 8; j++) acc8[j] *= f;
        #pragma unroll
        for (int q4 = 0; q4 < 32; q4 += 4) {
            float4 lv = *(const float4*)&At2[xr][q4];
            float le[4] = {lv.x, lv.y, lv.z, lv.w};
            #pragma unroll
            for (int u = 0; u < 4; u++) {
                float e = __expf(le[u] - m);
                l += e;
                float4 v0 = *(const float4*)&Vt[q4 + u][p * 8];
                float4 v1 = *(const float4*)&Vt[q4 + u][p * 8 + 4];
                acc8[0] = fmaf(e, v0.x, acc8[0]);
                acc8[1] = fmaf(e, v0.y, acc8[1]);
                acc8[2] = fmaf(e, v0.z, acc8[2]);
                acc8[3] = fmaf(e, v0.w, acc8[3]);
                acc8[4] = fmaf(e, v1.x, acc8[4]);
                acc8[5] = fmaf(e, v1.y, acc8[5]);
                acc8[6] = fmaf(e, v1.z, acc8[6]);
                acc8[7] = fmaf(e, v1.w, acc8[7]);
            }
        }
    }
    float inv = 1.f / l;
    float* dst = &x_att[((size_t)b * 4096 + x0 + xr) * 256 + h * 32 + p * 8];
    *(float4*)&dst[0] = make_float4(acc8[0] * inv, acc8[1] * inv, acc8[2] * inv, acc8[3] * inv);
    *(float4*)&dst[4] = make_float4(acc8[4] * inv, acc8[5] * inv, acc8[6] * inv, acc8[7] * inv);
}

// ---------------- final projection ----------------
__global__ __launch_bounds__(256) void proj_kernel(
    const float* __restrict__ A, const void* __restrict__ W, const void* __restrict__ bias,
    float* __restrict__ out, const int* __restrict__ flags)
{
    __shared__ __align__(16) float As[16][68];
    __shared__ __align__(16) float Bs[16][64];
    int bf = flags[1];
    const float* W32 = (const float*)W;
    const unsigned short* W16 = (const unsigned short*)W;
    int m0 = blockIdx.x * 64, n0 = blockIdx.y * 64;
    int id = threadIdx.x, tm = id >> 4, tn = id & 15;
    float acc[4][4] = {};
    for (int k0 = 0; k0 < 256; k0 += 16) {
        int rr = id >> 2, ck = (id & 3) * 4;
        int rk = id >> 4, cn = (id & 15) * 4;
        {
            float4 a4 = *(const float4*)&A[(size_t)(m0 + rr) * 256 + k0 + ck];
            As[ck + 0][rr] = a4.x; As[ck + 1][rr] = a4.y;
            As[ck + 2][rr] = a4.z; As[ck + 3][rr] = a4.w;
        }
        if (bf) {
            uint2 w2 = *(const uint2*)&W16[(size_t)(k0 + rk) * 256 + n0 + cn];
            Bs[rk][cn + 0] = b2f(w2.x & 0xFFFFu); Bs[rk][cn + 1] = b2f(w2.x >> 16);
            Bs[rk][cn + 2] = b2f(w2.y & 0xFFFFu); Bs[rk][cn + 3] = b2f(w2.y >> 16);
        } else {
            *(float4*)&Bs[rk][cn] = *(const float4*)&W32[(size_t)(k0 + rk) * 256 + n0 + cn];
        }
        __syncthreads();
        #pragma unroll
        for (int kk = 0; kk < 16; kk++) {
            float4 a = *(const float4*)&As[kk][tm * 4];
            float4 b = *(const float4*)&Bs[kk][tn * 4];
            float av[4] = {a.x, a.y, a.z, a.w};
            float bv[4] = {b.x, b.y, b.z, b.w};
            #pragma unroll
            for (int i = 0; i < 4; i++)
                #pragma unroll
                for (int j = 0; j < 4; j++)
                    acc[i][j] = fmaf(av[i], bv[j], acc[i][j]);
        }
        __syncthreads();
    }
    #pragma unroll
    for (int i = 0; i < 4; i++) {
        int col = n0 + tn * 4;
        float b0 = bf ? b2f(((const unsigned short*)bias)[col + 0]) : ((const float*)bias)[col + 0];
        float b1 = bf ? b2f(((const unsigned short*)bias)[col + 1]) : ((const float*)bias)[col + 1];
        float b2v = bf ? b2f(((const unsigned short*)bias)[col + 2]) : ((const float*)bias)[col + 2];
        float b3 = bf ? b2f(((const unsigned short*)bias)[col + 3]) : ((const float*)bias)[col + 3];
        float4 o = make_float4(acc[i][0] + b0, acc[i][1] + b1, acc[i][2] + b2v, acc[i][3] + b3);
        *(float4*)&out[(size_t)(m0 + tm * 4 + i) * 256 + col] = o;
    }
}

extern "C" void kernel_launch(void* const* d_in, const int* in_sizes, int n_in,
                              void* d_out, int out_size, void* d_ws, size_t ws_size,
                              hipStream_t stream) {
    (void)in_sizes; (void)n_in; (void)out_size; (void)ws_size;
    const void* x         = d_in[0];
    const void* kern      = d_in[1];
    const int*  rd        = (const int*)d_in[2];
    const int*  polar     = (const int*)d_in[3];
    const void* amask     = d_in[4];
    const void* w_qkv     = d_in[5];
    const void* w_proj    = d_in[6];
    const void* b_proj    = d_in[7];
    const void* polar_emb = d_in[8];
    const void* dis_emb   = d_in[9];
    float* out = (float*)d_out;

    float* ws = (float*)d_ws;
    float* S     = ws + OFF_S;
    float* xqT   = ws + OFF_XQT;
    float* xv    = ws + OFF_XV;
    float* xkT   = ws + OFF_XKT;
    float* kq    = ws + OFF_KQ;
    float* kkM   = ws + OFF_KK;
    float* kvM   = ws + OFF_KV;
    float* k_att = ws + OFF_KATT;
    float* x_att = ws + OFF_XATT;
    unsigned int* maskT = (unsigned int*)(ws + OFF_MT);
    int* mori   = (int*)(ws + OFF_MORI);
    float* osumP = ws + OFF_OSUMP;
    float* accP  = ws + OFF_ACCP;
    float2* mlP  = (float2*)(ws + OFF_MLP);
    int* flags  = (int*)(ws + OFF_FLAG);

    detect_kernel<<<2, 256, 0, stream>>>((const unsigned int*)amask, (const unsigned int*)x, flags);
    qkv2_kernel<<<dim3(128, 6), 256, 0, stream>>>(x, w_qkv, xqT, xkT, xv, flags);
    qkv_kernel<<<dim3(16, 12), 256, 0, stream>>>(kern, w_qkv, kq, kkM, kvM, flags);
    maskpack_kernel<<<4096, 256, 0, stream>>>(amask, maskT, flags);

    for (int bo = 0; bo < 4; bo += 2) {
        s1_kernel<<<dim3(64, 4, 16), 256, 0, stream>>>(kq, xkT, S, polar, osumP, bo);
        argmax_kernel<<<128, 256, 0, stream>>>(osumP, mori, bo);
        av1_kernel<<<dim3(16, 4, 16), 256, 0, stream>>>(S, xv, rd, polar, maskT,
                                                        dis_emb, polar_emb, mori, flags,
                                                        accP, mlP, bo);
        combine_kernel<<<dim3(4, 16), 256, 0, stream>>>(accP, mlP, k_att, bo);
        fa2_kernel<<<dim3(64, 16), 256, 0, stream>>>(kkM, xqT, kvM, rd, polar, maskT,
                                                     dis_emb, polar_emb, mori, flags, x_att, bo);
    }
    proj_kernel<<<dim3(256, 4), 256, 0, stream>>>(x_att, w_proj, b_proj, out, flags);
    proj_kernel<<<dim3(16, 4), 256, 0, stream>>>(k_att, w_proj, b_proj, out + 4194304, flags);
}

// Round 9
// 790.101 us; speedup vs baseline: 1.0423x; 1.0423x over previous
//
#include <hip/hip_runtime.h>
#include <hip/hip_bf16.h>

#define SCALE 0.17677669529663689f  // 32^-0.5

// ---------------- workspace offsets (in floats) ----------------
#define OFF_S    0UL          // 16,777,216 (one half: 16 bh x 256 k x 4096 x)
#define OFF_XQT  16777216UL   // 4,194,304
#define OFF_XV   20971520UL   // 4,194,304
#define OFF_XKT  25165824UL   // 4,194,304
#define OFF_KQ   29360128UL   // 262,144
#define OFF_KK   29622272UL   // 262,144
#define OFF_KV   29884416UL   // 262,144
#define OFF_KATT 30146560UL   // 262,144
#define OFF_XATT 30408704UL   // 4,194,304
#define OFF_MT   34603008UL   // maskT 4 MB
#define OFF_MORI 35651584UL   // 8192 ints
#define OFF_STAT 35659776UL   // 8192 float2 (row max, 1/sum) for path 1
#define OFF_FLAG 35676160UL

__device__ __forceinline__ float b2f(unsigned int u) {
    union { unsigned int i; float f; } v; v.i = u << 16; return v.f;
}

// ---------------- dtype detection ----------------
__global__ __launch_bounds__(256) void detect_kernel(
    const unsigned int* __restrict__ mask, const unsigned int* __restrict__ xf,
    int* __restrict__ flags)
{
    __shared__ unsigned int orv;
    __shared__ int cnt;
    int t = threadIdx.x;
    if (t == 0) { orv = 0u; cnt = 0; }
    __syncthreads();
    if (blockIdx.x == 0) {
        unsigned int v = 0;
        for (int i = t; i < 16384; i += 256) v |= mask[i];
        atomicOr(&orv, v);
        __syncthreads();
        if (t == 0) {
            unsigned int o = orv;
            int f;
            if (o <= 1u || o == 0x3F800000u) f = 0;
            else if (o & 0x00800080u)        f = 2;
            else                             f = 1;
            flags[0] = f;
        }
    } else {
        int c = 0;
        for (int i = t; i < 4096; i += 256) {
            unsigned int h = xf[i] & 0xFFFFu;
            unsigned int e = (h >> 7) & 0xFFu;
            if (h == 0u || (e >= 0x75u && e <= 0x82u)) c++;
        }
        atomicAdd(&cnt, c);
        __syncthreads();
        if (t == 0) flags[1] = (cnt > 3000) ? 1 : 0;
    }
}

// ---------------- qkv128: mode-0 GEMM, 128x64 tile, 8x4 microtile (split rows) ----
// A(16384x256) @ W(256x768); q,k -> [bh][d][4096] transposed; v -> [bh][x][32]
// Thread owns rows {tm*4..+3, 64+tm*4..+3} x cols {tn*4..+3}: all LDS reads
// lane-stride 4 words (2-way bank alias = free).
__global__ __launch_bounds__(256) void qkv128_kernel(
    const void* __restrict__ A, const void* __restrict__ W,
    float* __restrict__ oq, float* __restrict__ ok, float* __restrict__ ov,
    const int* __restrict__ flags)
{
    __shared__ __align__(16) float As[16][132];
    __shared__ __align__(16) float Bs[16][64];
    int bf = flags[1];
    const float* A32 = (const float*)A;
    const float* W32 = (const float*)W;
    const unsigned short* A16 = (const unsigned short*)A;
    const unsigned short* W16 = (const unsigned short*)W;
    int m0 = blockIdx.x * 128;
    int n0 = blockIdx.y * 64;
    int id = threadIdx.x;
    int tm = id >> 4, tn = id & 15;
    float acc[8][4] = {};
    for (int k0 = 0; k0 < 256; k0 += 16) {
        int r = id >> 1, ck = (id & 1) * 8;
        int rk = id >> 4, cn = (id & 15) * 4;
        if (bf) {
            uint4 a4 = *(const uint4*)&A16[(size_t)(m0 + r) * 256 + k0 + ck];
            As[ck + 0][r] = b2f(a4.x & 0xFFFFu); As[ck + 1][r] = b2f(a4.x >> 16);
            As[ck + 2][r] = b2f(a4.y & 0xFFFFu); As[ck + 3][r] = b2f(a4.y >> 16);
            As[ck + 4][r] = b2f(a4.z & 0xFFFFu); As[ck + 5][r] = b2f(a4.z >> 16);
            As[ck + 6][r] = b2f(a4.w & 0xFFFFu); As[ck + 7][r] = b2f(a4.w >> 16);
            uint2 w2 = *(const uint2*)&W16[(size_t)(k0 + rk) * 768 + n0 + cn];
            Bs[rk][cn + 0] = b2f(w2.x & 0xFFFFu); Bs[rk][cn + 1] = b2f(w2.x >> 16);
            Bs[rk][cn + 2] = b2f(w2.y & 0xFFFFu); Bs[rk][cn + 3] = b2f(w2.y >> 16);
        } else {
            float4 a0 = *(const float4*)&A32[(size_t)(m0 + r) * 256 + k0 + ck];
            float4 a1 = *(const float4*)&A32[(size_t)(m0 + r) * 256 + k0 + ck + 4];
            As[ck + 0][r] = a0.x; As[ck + 1][r] = a0.y;
            As[ck + 2][r] = a0.z; As[ck + 3][r] = a0.w;
            As[ck + 4][r] = a1.x; As[ck + 5][r] = a1.y;
            As[ck + 6][r] = a1.z; As[ck + 7][r] = a1.w;
            *(float4*)&Bs[rk][cn] = *(const float4*)&W32[(size_t)(k0 + rk) * 768 + n0 + cn];
        }
        __syncthreads();
        #pragma unroll
        for (int kk = 0; kk < 16; kk++) {
            float a[8], b[4];
            *(float4*)&a[0] = *(const float4*)&As[kk][tm * 4];
            *(float4*)&a[4] = *(const float4*)&As[kk][64 + tm * 4];
            *(float4*)&b[0] = *(const float4*)&Bs[kk][tn * 4];
            #pragma unroll
            for (int i = 0; i < 8; i++)
                #pragma unroll
                for (int j = 0; j < 4; j++)
                    acc[i][j] = fmaf(a[i], b[j], acc[i][j]);
        }
        __syncthreads();
    }
    int sec = n0 >> 8;
    int b = m0 >> 12;
    if (sec < 2) {
        int rr0 = (m0 & 4095) + tm * 4;
        float* dstb = (sec == 0) ? oq : ok;
        #pragma unroll
        for (int j = 0; j < 4; j++) {
            int col = n0 + tn * 4 + j;
            int hh = (col >> 5) & 7, d = col & 31;
            size_t base = (((size_t)(b * 8 + hh)) * 32 + d) * 4096 + rr0;
            *(float4*)&dstb[base]      = make_float4(acc[0][j], acc[1][j], acc[2][j], acc[3][j]);
            *(float4*)&dstb[base + 64] = make_float4(acc[4][j], acc[5][j], acc[6][j], acc[7][j]);
        }
    } else {
        int col0 = n0 + tn * 4;
        int hh = (col0 >> 5) & 7, d0 = col0 & 31;
        #pragma unroll
        for (int i = 0; i < 8; i++) {
            int rr = (m0 & 4095) + (i < 4 ? tm * 4 + i : 64 + tm * 4 + (i - 4));
            *(float4*)&ov[(((size_t)(b * 8 + hh)) * 4096 + rr) * 32 + d0] =
                make_float4(acc[i][0], acc[i][1], acc[i][2], acc[i][3]);
        }
    }
}

// ---------------- qkv (mode-1, kernal): 64x64 tile ----------------
__global__ __launch_bounds__(256) void qkv_kernel(
    const void* __restrict__ A, const void* __restrict__ W,
    float* __restrict__ oq, float* __restrict__ ok, float* __restrict__ ov,
    const int* __restrict__ flags)
{
    __shared__ __align__(16) float As[16][68];
    __shared__ __align__(16) float Bs[16][64];
    int bf = flags[1];
    const float* A32 = (const float*)A;
    const float* W32 = (const float*)W;
    const unsigned short* A16 = (const unsigned short*)A;
    const unsigned short* W16 = (const unsigned short*)W;
    int m0 = blockIdx.x * 64;
    int n0 = blockIdx.y * 64;
    int id = threadIdx.x;
    int tm = id >> 4, tn = id & 15;
    float acc[4][4] = {};
    for (int k0 = 0; k0 < 256; k0 += 16) {
        int r = id >> 2, ck = (id & 3) * 4;
        int rk = id >> 4, cn = (id & 15) * 4;
        if (bf) {
            uint2 a2 = *(const uint2*)&A16[(size_t)(m0 + r) * 256 + k0 + ck];
            As[ck + 0][r] = b2f(a2.x & 0xFFFFu); As[ck + 1][r] = b2f(a2.x >> 16);
            As[ck + 2][r] = b2f(a2.y & 0xFFFFu); As[ck + 3][r] = b2f(a2.y >> 16);
            uint2 w2 = *(const uint2*)&W16[(size_t)(k0 + rk) * 768 + n0 + cn];
            Bs[rk][cn + 0] = b2f(w2.x & 0xFFFFu); Bs[rk][cn + 1] = b2f(w2.x >> 16);
            Bs[rk][cn + 2] = b2f(w2.y & 0xFFFFu); Bs[rk][cn + 3] = b2f(w2.y >> 16);
        } else {
            float4 a4 = *(const float4*)&A32[(size_t)(m0 + r) * 256 + k0 + ck];
            As[ck + 0][r] = a4.x; As[ck + 1][r] = a4.y;
            As[ck + 2][r] = a4.z; As[ck + 3][r] = a4.w;
            *(float4*)&Bs[rk][cn] = *(const float4*)&W32[(size_t)(k0 + rk) * 768 + n0 + cn];
        }
        __syncthreads();
        #pragma unroll
        for (int kk = 0; kk < 16; kk++) {
            float4 a = *(const float4*)&As[kk][tm * 4];
            float4 b = *(const float4*)&Bs[kk][tn * 4];
            float av[4] = {a.x, a.y, a.z, a.w};
            float bv[4] = {b.x, b.y, b.z, b.w};
            #pragma unroll
            for (int i = 0; i < 4; i++)
                #pragma unroll
                for (int j = 0; j < 4; j++)
                    acc[i][j] = fmaf(av[i], bv[j], acc[i][j]);
        }
        __syncthreads();
    }
    #pragma unroll
    for (int i = 0; i < 4; i++) {
        int row = m0 + tm * 4 + i;
        int b = row >> 8, rr = row & 255;
        #pragma unroll
        for (int j = 0; j < 4; j++) {
            int col = n0 + tn * 4 + j;
            int s2 = col >> 8, hh = (col >> 5) & 7, d = col & 31;
            float* dst = s2 == 0 ? oq : (s2 == 1 ? ok : ov);
            dst[(((size_t)(b * 8 + hh)) * 256 + rr) * 32 + d] = acc[i][j];
        }
    }
}

// ---------------- mask bit-packing ----------------
__global__ __launch_bounds__(256) void maskpack_kernel(
    const void* __restrict__ mask, unsigned int* __restrict__ maskT,
    const int* __restrict__ flags)
{
    int bh = blockIdx.x >> 7;
    int x0 = (blockIdx.x & 127) * 32;
    int t = threadIdx.x;
    int wv = t >> 6, lane = t & 63;
    int mode = flags[0];
    __shared__ unsigned int lds[32][8];
    for (int it = 0; it < 8; it++) {
        int xl = wv * 8 + it;
        size_t rb = ((size_t)bh * 4096 + x0 + xl) * 256;
        unsigned int nib;
        if (mode == 0) {
            uint4 m = ((const uint4*)((const unsigned int*)mask + rb))[lane];
            nib = (unsigned int)(m.x != 0u) | ((unsigned int)(m.y != 0u) << 1)
                | ((unsigned int)(m.z != 0u) << 2) | ((unsigned int)(m.w != 0u) << 3);
        } else if (mode == 1) {
            unsigned int m = ((const unsigned int*)mask)[rb / 4 + lane];
            nib = (unsigned int)((m & 0xFFu) != 0u) | ((unsigned int)((m & 0xFF00u) != 0u) << 1)
                | ((unsigned int)((m & 0xFF0000u) != 0u) << 2)
                | ((unsigned int)((m & 0xFF000000u) != 0u) << 3);
        } else {
            uint2 m = ((const uint2*)((const unsigned short*)mask + rb))[lane];
            nib = (unsigned int)((m.x & 0xFFFFu) != 0u) | ((unsigned int)((m.x >> 16) != 0u) << 1)
                | ((unsigned int)((m.y & 0xFFFFu) != 0u) << 2)
                | ((unsigned int)((m.y >> 16) != 0u) << 3);
        }
        unsigned long long b0 = __ballot((nib & 1u) != 0u);
        unsigned long long b1 = __ballot((nib & 2u) != 0u);
        unsigned long long b2 = __ballot((nib & 4u) != 0u);
        unsigned long long b3 = __ballot((nib & 8u) != 0u);
        if (lane < 8) {
            int j = lane >> 1;
            unsigned long long bb = j == 0 ? b0 : j == 1 ? b1 : j == 2 ? b2 : b3;
            lds[xl][lane] = (lane & 1) ? (unsigned int)(bb >> 32) : (unsigned int)bb;
        }
    }
    __syncthreads();
    int widx = (t & 3) * 2 + (t >> 7);
    int bitpos = (t >> 2) & 31;
    unsigned int w = 0u;
    #pragma unroll
    for (int xl = 0; xl < 32; xl++)
        w |= ((lds[xl][widx] >> bitpos) & 1u) << xl;
    maskT[((size_t)bh * 256 + t) * 128 + (x0 >> 5)] = w;
}

// ---------------- S1 = scale * kq (256x32) @ xkT (32x4096), half-batch ----------------
__global__ __launch_bounds__(256) void s1_kernel(
    const float* __restrict__ kq, const float* __restrict__ xkT, float* __restrict__ S, int bo)
{
    __shared__ __align__(16) float Aq[32][68];
    __shared__ __align__(16) float Bs[32][64];
    int z = blockIdx.z;
    size_t bhg = (size_t)(bo * 8 + z);
    int k0 = blockIdx.y * 64;
    int x0 = blockIdx.x * 64;
    int id = threadIdx.x;
    {
        int c4 = (id & 7) * 4;
        #pragma unroll
        for (int rep = 0; rep < 2; rep++) {
            int r = (id >> 3) + rep * 32;
            float4 a = *(const float4*)&kq[(bhg * 256 + k0 + r) * 32 + c4];
            Aq[c4 + 0][r] = a.x; Aq[c4 + 1][r] = a.y;
            Aq[c4 + 2][r] = a.z; Aq[c4 + 3][r] = a.w;
        }
    }
    {
        int c = (id & 15) * 4;
        #pragma unroll
        for (int rep = 0; rep < 2; rep++) {
            int r = (id >> 4) + rep * 16;
            *(float4*)&Bs[r][c] = *(const float4*)&xkT[(bhg * 32 + r) * 4096 + x0 + c];
        }
    }
    __syncthreads();
    int tm = id >> 4, tn = id & 15;
    float acc[4][4] = {};
    #pragma unroll
    for (int dd = 0; dd < 32; dd++) {
        float4 a = *(const float4*)&Aq[dd][tm * 4];
        float4 b = *(const float4*)&Bs[dd][tn * 4];
        float av[4] = {a.x, a.y, a.z, a.w};
        float bv[4] = {b.x, b.y, b.z, b.w};
        #pragma unroll
        for (int i = 0; i < 4; i++)
            #pragma unroll
            for (int j = 0; j < 4; j++)
                acc[i][j] = fmaf(av[i], bv[j], acc[i][j]);
    }
    #pragma unroll
    for (int i = 0; i < 4; i++) {
        float4 o;
        o.x = acc[i][0] * SCALE; o.y = acc[i][1] * SCALE;
        o.z = acc[i][2] * SCALE; o.w = acc[i][3] * SCALE;
        *(float4*)&S[((size_t)z * 256 + k0 + tm * 4 + i) * 4096 + x0 + tn * 4] = o;
    }
}

// ---------------- path-1: orientation argmax + row stats (NO S write) ----------------
__global__ __launch_bounds__(256) void p1_softmax_kernel(
    const float* __restrict__ S,
    const int* __restrict__ rd, const int* __restrict__ polar,
    const unsigned int* __restrict__ maskT,
    const void* __restrict__ dis_emb, const void* __restrict__ polar_emb,
    int* __restrict__ mori, float2* __restrict__ stats,
    const int* __restrict__ flags, int bo)
{
    int idx = blockIdx.x;
    int b2i = idx >> 11;
    int k = (idx >> 3) & 255;
    int h = idx & 7;
    int b = bo + b2i;
    int bh = b * 8 + h;
    int bhk = bh * 256 + k;
    int bhkl = (b2i * 8 + h) * 256 + k;
    int t = threadIdx.x;
    int bf = flags[1];
    __shared__ float disc[66];
    __shared__ float pem[8];
    __shared__ float osum[8];
    __shared__ float red[8];
    __shared__ int mo_s;
    if (t < 66) disc[t] = bf ? b2f(((const unsigned short*)dis_emb)[t * 8 + h])
                             : ((const float*)dis_emb)[t * 8 + h];
    if (t < 8) {
        pem[t] = bf ? b2f(((const unsigned short*)polar_emb)[t])
                    : ((const float*)polar_emb)[t];
        osum[t] = 0.f;
    }
    __syncthreads();

    const float* srow = &S[(size_t)bhkl * 4096];
    const int* prow = &polar[((size_t)b * 256 + k) * 4096];
    const int* rrow = &rd[((size_t)b * 256 + k) * 4096];

    float s[16]; int po[16];
    float loc[8] = {0.f, 0.f, 0.f, 0.f, 0.f, 0.f, 0.f, 0.f};
    #pragma unroll
    for (int i = 0; i < 16; i++) {
        int x = t + i * 256;
        s[i] = srow[x];
        int p = prow[x];
        p = p < 0 ? 0 : (p > 7 ? 7 : p);
        po[i] = p;
        float a = fabsf(s[i]);
        #pragma unroll
        for (int o = 0; o < 8; o++) loc[o] += (p == o) ? a : 0.f;
    }
    #pragma unroll
    for (int o = 0; o < 8; o++) {
        float v = loc[o];
        #pragma unroll
        for (int m = 32; m; m >>= 1) v += __shfl_xor(v, m);
        if ((t & 63) == 0) atomicAdd(&osum[o], v);
    }
    __syncthreads();
    if (t == 0) {
        float best = osum[0]; int bi = 0;
        #pragma unroll
        for (int o = 1; o < 8; o++) if (osum[o] > best) { best = osum[o]; bi = o; }
        mo_s = bi;
        mori[bhk] = bi;
    }
    __syncthreads();
    int mo = mo_s;
    const unsigned int* mrow = &maskT[(size_t)bhk * 128];
    float mx = -3.4e38f;
    #pragma unroll
    for (int i = 0; i < 16; i++) {
        int x = t + i * 256;
        float bias = disc[rrow[x]] + pem[(po[i] - mo + 8) & 7];
        unsigned int w = mrow[x >> 5];
        float l = (((w >> (x & 31)) & 1u) ? -1e6f : s[i]) + bias;
        s[i] = l;
        mx = fmaxf(mx, l);
    }
    #pragma unroll
    for (int m = 32; m; m >>= 1) mx = fmaxf(mx, __shfl_xor(mx, m));
    if ((t & 63) == 0) red[t >> 6] = mx;
    __syncthreads();
    mx = fmaxf(fmaxf(red[0], red[1]), fmaxf(red[2], red[3]));
    float sum = 0.f;
    #pragma unroll
    for (int i = 0; i < 16; i++) { sum += __expf(s[i] - mx); }
    #pragma unroll
    for (int m = 32; m; m >>= 1) sum += __shfl_xor(sum, m);
    if ((t & 63) == 0) red[4 + (t >> 6)] = sum;
    __syncthreads();
    sum = red[4] + red[5] + red[6] + red[7];
    if (t == 0) stats[bhk] = make_float2(mx, 1.f / sum);
}

// ---------------- av1: (bias+exp fused) A @ xv -> k_att (16 x-splits, atomics) ----
__global__ __launch_bounds__(256) void av1_kernel(
    const float* __restrict__ S, const float* __restrict__ xv, float* __restrict__ k_att,
    const int* __restrict__ rd, const int* __restrict__ polar,
    const unsigned int* __restrict__ maskT,
    const void* __restrict__ dis_emb, const void* __restrict__ polar_emb,
    const int* __restrict__ mori, const float2* __restrict__ stats,
    const int* __restrict__ flags, int bo)
{
    __shared__ __align__(16) float At[64][68];
    __shared__ __align__(16) float Vt[64][32];
    __shared__ float disc[66];
    __shared__ float pem[8];
    __shared__ int mo_l[64];
    __shared__ float mx_l[64];
    __shared__ float inv_l[64];
    int z = blockIdx.z;
    int bhg = bo * 8 + z, b = bhg >> 3, h = bhg & 7;
    int k0 = blockIdx.y * 64;
    int xs = blockIdx.x;
    int id = threadIdx.x;
    int bf = flags[1];
    if (id < 66) disc[id] = bf ? b2f(((const unsigned short*)dis_emb)[id * 8 + h])
                               : ((const float*)dis_emb)[id * 8 + h];
    if (id < 8) pem[id] = bf ? b2f(((const unsigned short*)polar_emb)[id])
                             : ((const float*)polar_emb)[id];
    if (id < 64) {
        mo_l[id] = mori[(size_t)bhg * 256 + k0 + id];
        float2 st = stats[(size_t)bhg * 256 + k0 + id];
        mx_l[id] = st.x; inv_l[id] = st.y;
    }
    __syncthreads();
    int r = id >> 2, p = id & 3;
    float acc[8] = {};
    for (int c8 = 0; c8 < 4; c8++) {
        int xc = xs * 256 + c8 * 64;
        if (c8) __syncthreads();
        {
            int c = (id & 15) * 4;
            #pragma unroll
            for (int rep = 0; rep < 4; rep++) {
                int rr = (id >> 4) + rep * 16;
                int kg = k0 + rr;
                float4 s4 = *(const float4*)&S[((size_t)z * 256 + kg) * 4096 + xc + c];
                size_t rib = ((size_t)b * 256 + kg) * 4096 + xc + c;
                int4 r4 = *(const int4*)&rd[rib];
                int4 p4 = *(const int4*)&polar[rib];
                unsigned int mw = maskT[((size_t)bhg * 256 + kg) * 128 + ((xc + c) >> 5)];
                int mo = mo_l[rr];
                float mx = mx_l[rr];
                float sv[4] = {s4.x, s4.y, s4.z, s4.w};
                int rv[4] = {r4.x, r4.y, r4.z, r4.w};
                int pv[4] = {p4.x, p4.y, p4.z, p4.w};
                float e[4];
                #pragma unroll
                for (int j = 0; j < 4; j++) {
                    int pp = pv[j];
                    pp = pp < 0 ? 0 : (pp > 7 ? 7 : pp);
                    float bias = disc[rv[j]] + pem[(pp - mo + 8) & 7];
                    float l = (((mw >> ((xc + c + j) & 31)) & 1u) ? -1e6f : sv[j]) + bias;
                    e[j] = __expf(l - mx);
                }
                *(float4*)&At[rr][c] = make_float4(e[0], e[1], e[2], e[3]);
            }
        }
        {
            int c = (id & 7) * 4;
            #pragma unroll
            for (int rep = 0; rep < 2; rep++) {
                int rr = (id >> 3) + rep * 32;
                *(float4*)&Vt[rr][c] = *(const float4*)&xv[((size_t)bhg * 4096 + xc + rr) * 32 + c];
            }
        }
        __syncthreads();
        #pragma unroll
        for (int q4 = 0; q4 < 64; q4 += 4) {
            float4 av = *(const float4*)&At[r][q4];
            float aa[4] = {av.x, av.y, av.z, av.w};
            #pragma unroll
            for (int u = 0; u < 4; u++) {
                float4 v0 = *(const float4*)&Vt[q4 + u][p * 8];
                float4 v1 = *(const float4*)&Vt[q4 + u][p * 8 + 4];
                acc[0] = fmaf(aa[u], v0.x, acc[0]);
                acc[1] = fmaf(aa[u], v0.y, acc[1]);
                acc[2] = fmaf(aa[u], v0.z, acc[2]);
                acc[3] = fmaf(aa[u], v0.w, acc[3]);
                acc[4] = fmaf(aa[u], v1.x, acc[4]);
                acc[5] = fmaf(aa[u], v1.y, acc[5]);
                acc[6] = fmaf(aa[u], v1.z, acc[6]);
                acc[7] = fmaf(aa[u], v1.w, acc[7]);
            }
        }
    }
    float inv = inv_l[r];
    float* dst = &k_att[((size_t)b * 256 + k0 + r) * 256 + h * 32 + p * 8];
    #pragma unroll
    for (int j = 0; j < 8; j++) atomicAdd(&dst[j], acc[j] * inv);
}

// ---------------- fa2: kc=32 chunks, transposed P tile, float4 consumption ----
__global__ __launch_bounds__(256) void fa2_kernel(
    const float* __restrict__ kk, const float* __restrict__ xqT, const float* __restrict__ kv,
    const int* __restrict__ rd, const int* __restrict__ polar,
    const unsigned int* __restrict__ maskT,
    const void* __restrict__ dis_emb, const void* __restrict__ polar_emb,
    const int* __restrict__ mori, const int* __restrict__ flags,
    float* __restrict__ x_att, int bo)
{
    __shared__ __align__(16) float Aq[32][34];
    __shared__ __align__(16) float Bs[32][64];
    __shared__ __align__(16) float At2[64][34];
    __shared__ __align__(16) float Vt[32][32];
    __shared__ float disc[66];
    __shared__ float pem[8];
    __shared__ int mo_l[256];
    int z = blockIdx.y;
    int bhg = bo * 8 + z, b = bhg >> 3, h = bhg & 7;
    int x0 = blockIdx.x * 64;
    int id = threadIdx.x;
    int bf = flags[1];
    if (id < 66) disc[id] = bf ? b2f(((const unsigned short*)dis_emb)[id * 8 + h])
                               : ((const float*)dis_emb)[id * 8 + h];
    if (id < 8) pem[id] = bf ? b2f(((const unsigned short*)polar_emb)[id])
                             : ((const float*)polar_emb)[id];
    mo_l[id] = mori[(size_t)bhg * 256 + id];
    {
        int c = (id & 15) * 4;
        #pragma unroll
        for (int rep = 0; rep < 2; rep++) {
            int r = (id >> 4) + rep * 16;
            *(float4*)&Bs[r][c] = *(const float4*)&xqT[((size_t)bhg * 32 + r) * 4096 + x0 + c];
        }
    }
    int tm = id >> 4, tn = id & 15;
    int xr = id >> 2, p = id & 3;
    float acc8[8] = {};
    float m = -3.0e38f, l = 0.f;
    for (int kc = 0; kc < 256; kc += 32) {
        __syncthreads();
        {
            int r = id >> 3, c4 = (id & 7) * 4;
            float4 a = *(const float4*)&kk[((size_t)bhg * 256 + kc + r) * 32 + c4];
            Aq[c4 + 0][r] = a.x; Aq[c4 + 1][r] = a.y;
            Aq[c4 + 2][r] = a.z; Aq[c4 + 3][r] = a.w;
            *(float4*)&Vt[r][c4] = *(const float4*)&kv[((size_t)bhg * 256 + kc + r) * 32 + c4];
        }
        __syncthreads();
        float acc[2][4] = {};
        #pragma unroll
        for (int dd = 0; dd < 32; dd++) {
            float2 a2 = *(const float2*)&Aq[dd][tm * 2];
            float4 b4 = *(const float4*)&Bs[dd][tn * 4];
            float bv[4] = {b4.x, b4.y, b4.z, b4.w};
            #pragma unroll
            for (int j = 0; j < 4; j++) {
                acc[0][j] = fmaf(a2.x, bv[j], acc[0][j]);
                acc[1][j] = fmaf(a2.y, bv[j], acc[1][j]);
            }
        }
        int xb = x0 + tn * 4;
        #pragma unroll
        for (int i = 0; i < 2; i++) {
            int kl = tm * 2 + i;
            int k = kc + kl;
            int mo = mo_l[k];
            size_t rib = ((size_t)b * 256 + k) * 4096 + xb;
            int4 r4 = *(const int4*)&rd[rib];
            int4 p4 = *(const int4*)&polar[rib];
            unsigned int mw = maskT[((size_t)bhg * 256 + k) * 128 + (xb >> 5)];
            int rv[4] = {r4.x, r4.y, r4.z, r4.w};
            int pv[4] = {p4.x, p4.y, p4.z, p4.w};
            #pragma unroll
            for (int j = 0; j < 4; j++) {
                int pp = pv[j];
                pp = pp < 0 ? 0 : (pp > 7 ? 7 : pp);
                float bias = disc[rv[j]] + pem[(pp - mo + 8) & 7];
                float s = acc[i][j] * SCALE;
                At2[tn * 4 + j][kl] =
                    (((mw >> ((xb + j) & 31)) & 1u) ? -1e9f : s) + bias;
            }
        }
        __syncthreads();
        float mc = -3.0e38f;
        #pragma unroll
        for (int q4 = 0; q4 < 32; q4 += 4) {
            float4 v = *(const float4*)&At2[xr][q4];
            mc = fmaxf(mc, fmaxf(fmaxf(v.x, v.y), fmaxf(v.z, v.w)));
        }
        float mn = fmaxf(m, mc);
        float f = __expf(m - mn);
        m = mn;
        l *= f;
        #pragma unroll
        for (int j = 0; j < 8; j++) acc8[j] *= f;
        #pragma unroll
        for (int q4 = 0; q4 < 32; q4 += 4) {
            float4 lv = *(const float4*)&At2[xr][q4];
            float le[4] = {lv.x, lv.y, lv.z, lv.w};
            #pragma unroll
            for (int u = 0; u < 4; u++) {
                float e = __expf(le[u] - m);
                l += e;
                float4 v0 = *(const float4*)&Vt[q4 + u][p * 8];
                float4 v1 = *(const float4*)&Vt[q4 + u][p * 8 + 4];
                acc8[0] = fmaf(e, v0.x, acc8[0]);
                acc8[1] = fmaf(e, v0.y, acc8[1]);
                acc8[2] = fmaf(e, v0.z, acc8[2]);
                acc8[3] = fmaf(e, v0.w, acc8[3]);
                acc8[4] = fmaf(e, v1.x, acc8[4]);
                acc8[5] = fmaf(e, v1.y, acc8[5]);
                acc8[6] = fmaf(e, v1.z, acc8[6]);
                acc8[7] = fmaf(e, v1.w, acc8[7]);
            }
        }
    }
    float inv = 1.f / l;
    float* dst = &x_att[((size_t)b * 4096 + x0 + xr) * 256 + h * 32 + p * 8];
    *(float4*)&dst[0] = make_float4(acc8[0] * inv, acc8[1] * inv, acc8[2] * inv, acc8[3] * inv);
    *(float4*)&dst[4] = make_float4(acc8[4] * inv, acc8[5] * inv, acc8[6] * inv, acc8[7] * inv);
}

// ---------------- final projection ----------------
__global__ __launch_bounds__(256) void proj_kernel(
    const float* __restrict__ A, const void* __restrict__ W, const void* __restrict__ bias,
    float* __restrict__ out, const int* __restrict__ flags)
{
    __shared__ __align__(16) float As[16][68];
    __shared__ __align__(16) float Bs[16][64];
    int bf = flags[1];
    const float* W32 = (const float*)W;
    const unsigned short* W16 = (const unsigned short*)W;
    int m0 = blockIdx.x * 64, n0 = blockIdx.y * 64;
    int id = threadIdx.x, tm = id >> 4, tn = id & 15;
    float acc[4][4] = {};
    for (int k0 = 0; k0 < 256; k0 += 16) {
        int rr = id >> 2, ck = (id & 3) * 4;
        int rk = id >> 4, cn = (id & 15) * 4;
        {
            float4 a4 = *(const float4*)&A[(size_t)(m0 + rr) * 256 + k0 + ck];
            As[ck + 0][rr] = a4.x; As[ck + 1][rr] = a4.y;
            As[ck + 2][rr] = a4.z; As[ck + 3][rr] = a4.w;
        }
        if (bf) {
            uint2 w2 = *(const uint2*)&W16[(size_t)(k0 + rk) * 256 + n0 + cn];
            Bs[rk][cn + 0] = b2f(w2.x & 0xFFFFu); Bs[rk][cn + 1] = b2f(w2.x >> 16);
            Bs[rk][cn + 2] = b2f(w2.y & 0xFFFFu); Bs[rk][cn + 3] = b2f(w2.y >> 16);
        } else {
            *(float4*)&Bs[rk][cn] = *(const float4*)&W32[(size_t)(k0 + rk) * 256 + n0 + cn];
        }
        __syncthreads();
        #pragma unroll
        for (int kk = 0; kk < 16; kk++) {
            float4 a = *(const float4*)&As[kk][tm * 4];
            float4 b = *(const float4*)&Bs[kk][tn * 4];
            float av[4] = {a.x, a.y, a.z, a.w};
            float bv[4] = {b.x, b.y, b.z, b.w};
            #pragma unroll
            for (int i = 0; i < 4; i++)
                #pragma unroll
                for (int j = 0; j < 4; j++)
                    acc[i][j] = fmaf(av[i], bv[j], acc[i][j]);
        }
        __syncthreads();
    }
    #pragma unroll
    for (int i = 0; i < 4; i++) {
        int col = n0 + tn * 4;
        float b0 = bf ? b2f(((const unsigned short*)bias)[col + 0]) : ((const float*)bias)[col + 0];
        float b1 = bf ? b2f(((const unsigned short*)bias)[col + 1]) : ((const float*)bias)[col + 1];
        float b2v = bf ? b2f(((const unsigned short*)bias)[col + 2]) : ((const float*)bias)[col + 2];
        float b3 = bf ? b2f(((const unsigned short*)bias)[col + 3]) : ((const float*)bias)[col + 3];
        float4 o = make_float4(acc[i][0] + b0, acc[i][1] + b1, acc[i][2] + b2v, acc[i][3] + b3);
        *(float4*)&out[(size_t)(m0 + tm * 4 + i) * 256 + col] = o;
    }
}

extern "C" void kernel_launch(void* const* d_in, const int* in_sizes, int n_in,
                              void* d_out, int out_size, void* d_ws, size_t ws_size,
                              hipStream_t stream) {
    (void)in_sizes; (void)n_in; (void)out_size; (void)ws_size;
    const void* x         = d_in[0];
    const void* kern      = d_in[1];
    const int*  rd        = (const int*)d_in[2];
    const int*  polar     = (const int*)d_in[3];
    const void* amask     = d_in[4];
    const void* w_qkv     = d_in[5];
    const void* w_proj    = d_in[6];
    const void* b_proj    = d_in[7];
    const void* polar_emb = d_in[8];
    const void* dis_emb   = d_in[9];
    float* out = (float*)d_out;

    float* ws = (float*)d_ws;
    float* S     = ws + OFF_S;
    float* xqT   = ws + OFF_XQT;
    float* xv    = ws + OFF_XV;
    float* xkT   = ws + OFF_XKT;
    float* kq    = ws + OFF_KQ;
    float* kkM   = ws + OFF_KK;
    float* kvM   = ws + OFF_KV;
    float* k_att = ws + OFF_KATT;
    float* x_att = ws + OFF_XATT;
    unsigned int* maskT = (unsigned int*)(ws + OFF_MT);
    int* mori  = (int*)(ws + OFF_MORI);
    float2* stats = (float2*)(ws + OFF_STAT);
    int* flags = (int*)(ws + OFF_FLAG);

    detect_kernel<<<2, 256, 0, stream>>>((const unsigned int*)amask, (const unsigned int*)x, flags);
    qkv128_kernel<<<dim3(128, 12), 256, 0, stream>>>(x, w_qkv, xqT, xkT, xv, flags);
    qkv_kernel<<<dim3(16, 12), 256, 0, stream>>>(kern, w_qkv, kq, kkM, kvM, flags);
    maskpack_kernel<<<4096, 256, 0, stream>>>(amask, maskT, flags);
    hipMemsetAsync(k_att, 0, 262144 * sizeof(float), stream);

    for (int bo = 0; bo < 4; bo += 2) {
        s1_kernel<<<dim3(64, 4, 16), 256, 0, stream>>>(kq, xkT, S, bo);
        p1_softmax_kernel<<<4096, 256, 0, stream>>>(S, rd, polar, maskT, dis_emb, polar_emb,
                                                    mori, stats, flags, bo);
        av1_kernel<<<dim3(16, 4, 16), 256, 0, stream>>>(S, xv, k_att, rd, polar, maskT,
                                                        dis_emb, polar_emb, mori, stats, flags, bo);
        fa2_kernel<<<dim3(64, 16), 256, 0, stream>>>(kkM, xqT, kvM, rd, polar, maskT,
                                                     dis_emb, polar_emb, mori, flags, x_att, bo);
    }
    proj_kernel<<<dim3(256, 4), 256, 0, stream>>>(x_att, w_proj, b_proj, out, flags);
    proj_kernel<<<dim3(16, 4), 256, 0, stream>>>(k_att, w_proj, b_proj, out + 4194304, flags);
}

// Round 10
// 749.007 us; speedup vs baseline: 1.0995x; 1.0549x over previous
//
#include <hip/hip_runtime.h>
#include <hip/hip_bf16.h>

#define SCALE 0.17677669529663689f  // 32^-0.5

// ---------------- workspace offsets (in floats), total ~210 MB ----------------
#define OFF_S    0UL          // 33,554,432 (FULL batch: 32 bh x 256 k x 4096 x)
#define OFF_XQT  33554432UL   // 4,194,304
#define OFF_XV   37748736UL   // 4,194,304
#define OFF_XKT  41943040UL   // 4,194,304
#define OFF_KQ   46137344UL   // 262,144
#define OFF_KK   46399488UL   // 262,144
#define OFF_KV   46661632UL   // 262,144
#define OFF_KATT 46923776UL   // 262,144
#define OFF_XATT 47185920UL   // 4,194,304
#define OFF_MT   51380224UL   // maskT 4 MB
#define OFF_MORI 52428800UL   // 8192 ints
#define OFF_STAT 52436992UL   // 8192 float2
#define OFF_FLAG 52453376UL

__device__ __forceinline__ float b2f(unsigned int u) {
    union { unsigned int i; float f; } v; v.i = u << 16; return v.f;
}

// ---------------- dtype detection ----------------
__global__ __launch_bounds__(256) void detect_kernel(
    const unsigned int* __restrict__ mask, const unsigned int* __restrict__ xf,
    int* __restrict__ flags)
{
    __shared__ unsigned int orv;
    __shared__ int cnt;
    int t = threadIdx.x;
    if (t == 0) { orv = 0u; cnt = 0; }
    __syncthreads();
    if (blockIdx.x == 0) {
        unsigned int v = 0;
        for (int i = t; i < 16384; i += 256) v |= mask[i];
        atomicOr(&orv, v);
        __syncthreads();
        if (t == 0) {
            unsigned int o = orv;
            int f;
            if (o <= 1u || o == 0x3F800000u) f = 0;
            else if (o & 0x00800080u)        f = 2;
            else                             f = 1;
            flags[0] = f;
        }
    } else {
        int c = 0;
        for (int i = t; i < 4096; i += 256) {
            unsigned int h = xf[i] & 0xFFFFu;
            unsigned int e = (h >> 7) & 0xFFu;
            if (h == 0u || (e >= 0x75u && e <= 0x82u)) c++;
        }
        atomicAdd(&cnt, c);
        __syncthreads();
        if (t == 0) flags[1] = (cnt > 3000) ? 1 : 0;
    }
}

// ---------------- qkv128: mode-0 GEMM, 128x64 tile, 8x4 microtile (split rows) ----
__global__ __launch_bounds__(256) void qkv128_kernel(
    const void* __restrict__ A, const void* __restrict__ W,
    float* __restrict__ oq, float* __restrict__ ok, float* __restrict__ ov,
    const int* __restrict__ flags)
{
    __shared__ __align__(16) float As[16][132];
    __shared__ __align__(16) float Bs[16][64];
    int bf = flags[1];
    const float* A32 = (const float*)A;
    const float* W32 = (const float*)W;
    const unsigned short* A16 = (const unsigned short*)A;
    const unsigned short* W16 = (const unsigned short*)W;
    int m0 = blockIdx.x * 128;
    int n0 = blockIdx.y * 64;
    int id = threadIdx.x;
    int tm = id >> 4, tn = id & 15;
    float acc[8][4] = {};
    for (int k0 = 0; k0 < 256; k0 += 16) {
        int r = id >> 1, ck = (id & 1) * 8;
        int rk = id >> 4, cn = (id & 15) * 4;
        if (bf) {
            uint4 a4 = *(const uint4*)&A16[(size_t)(m0 + r) * 256 + k0 + ck];
            As[ck + 0][r] = b2f(a4.x & 0xFFFFu); As[ck + 1][r] = b2f(a4.x >> 16);
            As[ck + 2][r] = b2f(a4.y & 0xFFFFu); As[ck + 3][r] = b2f(a4.y >> 16);
            As[ck + 4][r] = b2f(a4.z & 0xFFFFu); As[ck + 5][r] = b2f(a4.z >> 16);
            As[ck + 6][r] = b2f(a4.w & 0xFFFFu); As[ck + 7][r] = b2f(a4.w >> 16);
            uint2 w2 = *(const uint2*)&W16[(size_t)(k0 + rk) * 768 + n0 + cn];
            Bs[rk][cn + 0] = b2f(w2.x & 0xFFFFu); Bs[rk][cn + 1] = b2f(w2.x >> 16);
            Bs[rk][cn + 2] = b2f(w2.y & 0xFFFFu); Bs[rk][cn + 3] = b2f(w2.y >> 16);
        } else {
            float4 a0 = *(const float4*)&A32[(size_t)(m0 + r) * 256 + k0 + ck];
            float4 a1 = *(const float4*)&A32[(size_t)(m0 + r) * 256 + k0 + ck + 4];
            As[ck + 0][r] = a0.x; As[ck + 1][r] = a0.y;
            As[ck + 2][r] = a0.z; As[ck + 3][r] = a0.w;
            As[ck + 4][r] = a1.x; As[ck + 5][r] = a1.y;
            As[ck + 6][r] = a1.z; As[ck + 7][r] = a1.w;
            *(float4*)&Bs[rk][cn] = *(const float4*)&W32[(size_t)(k0 + rk) * 768 + n0 + cn];
        }
        __syncthreads();
        #pragma unroll
        for (int kk = 0; kk < 16; kk++) {
            float a[8], b[4];
            *(float4*)&a[0] = *(const float4*)&As[kk][tm * 4];
            *(float4*)&a[4] = *(const float4*)&As[kk][64 + tm * 4];
            *(float4*)&b[0] = *(const float4*)&Bs[kk][tn * 4];
            #pragma unroll
            for (int i = 0; i < 8; i++)
                #pragma unroll
                for (int j = 0; j < 4; j++)
                    acc[i][j] = fmaf(a[i], b[j], acc[i][j]);
        }
        __syncthreads();
    }
    int sec = n0 >> 8;
    int b = m0 >> 12;
    if (sec < 2) {
        int rr0 = (m0 & 4095) + tm * 4;
        float* dstb = (sec == 0) ? oq : ok;
        #pragma unroll
        for (int j = 0; j < 4; j++) {
            int col = n0 + tn * 4 + j;
            int hh = (col >> 5) & 7, d = col & 31;
            size_t base = (((size_t)(b * 8 + hh)) * 32 + d) * 4096 + rr0;
            *(float4*)&dstb[base]      = make_float4(acc[0][j], acc[1][j], acc[2][j], acc[3][j]);
            *(float4*)&dstb[base + 64] = make_float4(acc[4][j], acc[5][j], acc[6][j], acc[7][j]);
        }
    } else {
        int col0 = n0 + tn * 4;
        int hh = (col0 >> 5) & 7, d0 = col0 & 31;
        #pragma unroll
        for (int i = 0; i < 8; i++) {
            int rr = (m0 & 4095) + (i < 4 ? tm * 4 + i : 64 + tm * 4 + (i - 4));
            *(float4*)&ov[(((size_t)(b * 8 + hh)) * 4096 + rr) * 32 + d0] =
                make_float4(acc[i][0], acc[i][1], acc[i][2], acc[i][3]);
        }
    }
}

// ---------------- qkv (mode-1, kernal): 64x64 tile ----------------
__global__ __launch_bounds__(256) void qkv_kernel(
    const void* __restrict__ A, const void* __restrict__ W,
    float* __restrict__ oq, float* __restrict__ ok, float* __restrict__ ov,
    const int* __restrict__ flags)
{
    __shared__ __align__(16) float As[16][68];
    __shared__ __align__(16) float Bs[16][64];
    int bf = flags[1];
    const float* A32 = (const float*)A;
    const float* W32 = (const float*)W;
    const unsigned short* A16 = (const unsigned short*)A;
    const unsigned short* W16 = (const unsigned short*)W;
    int m0 = blockIdx.x * 64;
    int n0 = blockIdx.y * 64;
    int id = threadIdx.x;
    int tm = id >> 4, tn = id & 15;
    float acc[4][4] = {};
    for (int k0 = 0; k0 < 256; k0 += 16) {
        int r = id >> 2, ck = (id & 3) * 4;
        int rk = id >> 4, cn = (id & 15) * 4;
        if (bf) {
            uint2 a2 = *(const uint2*)&A16[(size_t)(m0 + r) * 256 + k0 + ck];
            As[ck + 0][r] = b2f(a2.x & 0xFFFFu); As[ck + 1][r] = b2f(a2.x >> 16);
            As[ck + 2][r] = b2f(a2.y & 0xFFFFu); As[ck + 3][r] = b2f(a2.y >> 16);
            uint2 w2 = *(const uint2*)&W16[(size_t)(k0 + rk) * 768 + n0 + cn];
            Bs[rk][cn + 0] = b2f(w2.x & 0xFFFFu); Bs[rk][cn + 1] = b2f(w2.x >> 16);
            Bs[rk][cn + 2] = b2f(w2.y & 0xFFFFu); Bs[rk][cn + 3] = b2f(w2.y >> 16);
        } else {
            float4 a4 = *(const float4*)&A32[(size_t)(m0 + r) * 256 + k0 + ck];
            As[ck + 0][r] = a4.x; As[ck + 1][r] = a4.y;
            As[ck + 2][r] = a4.z; As[ck + 3][r] = a4.w;
            *(float4*)&Bs[rk][cn] = *(const float4*)&W32[(size_t)(k0 + rk) * 768 + n0 + cn];
        }
        __syncthreads();
        #pragma unroll
        for (int kk = 0; kk < 16; kk++) {
            float4 a = *(const float4*)&As[kk][tm * 4];
            float4 b = *(const float4*)&Bs[kk][tn * 4];
            float av[4] = {a.x, a.y, a.z, a.w};
            float bv[4] = {b.x, b.y, b.z, b.w};
            #pragma unroll
            for (int i = 0; i < 4; i++)
                #pragma unroll
                for (int j = 0; j < 4; j++)
                    acc[i][j] = fmaf(av[i], bv[j], acc[i][j]);
        }
        __syncthreads();
    }
    #pragma unroll
    for (int i = 0; i < 4; i++) {
        int row = m0 + tm * 4 + i;
        int b = row >> 8, rr = row & 255;
        #pragma unroll
        for (int j = 0; j < 4; j++) {
            int col = n0 + tn * 4 + j;
            int s2 = col >> 8, hh = (col >> 5) & 7, d = col & 31;
            float* dst = s2 == 0 ? oq : (s2 == 1 ? ok : ov);
            dst[(((size_t)(b * 8 + hh)) * 256 + rr) * 32 + d] = acc[i][j];
        }
    }
}

// ---------------- mask bit-packing ----------------
__global__ __launch_bounds__(256) void maskpack_kernel(
    const void* __restrict__ mask, unsigned int* __restrict__ maskT,
    const int* __restrict__ flags)
{
    int bh = blockIdx.x >> 7;
    int x0 = (blockIdx.x & 127) * 32;
    int t = threadIdx.x;
    int wv = t >> 6, lane = t & 63;
    int mode = flags[0];
    __shared__ unsigned int lds[32][8];
    for (int it = 0; it < 8; it++) {
        int xl = wv * 8 + it;
        size_t rb = ((size_t)bh * 4096 + x0 + xl) * 256;
        unsigned int nib;
        if (mode == 0) {
            uint4 m = ((const uint4*)((const unsigned int*)mask + rb))[lane];
            nib = (unsigned int)(m.x != 0u) | ((unsigned int)(m.y != 0u) << 1)
                | ((unsigned int)(m.z != 0u) << 2) | ((unsigned int)(m.w != 0u) << 3);
        } else if (mode == 1) {
            unsigned int m = ((const unsigned int*)mask)[rb / 4 + lane];
            nib = (unsigned int)((m & 0xFFu) != 0u) | ((unsigned int)((m & 0xFF00u) != 0u) << 1)
                | ((unsigned int)((m & 0xFF0000u) != 0u) << 2)
                | ((unsigned int)((m & 0xFF000000u) != 0u) << 3);
        } else {
            uint2 m = ((const uint2*)((const unsigned short*)mask + rb))[lane];
            nib = (unsigned int)((m.x & 0xFFFFu) != 0u) | ((unsigned int)((m.x >> 16) != 0u) << 1)
                | ((unsigned int)((m.y & 0xFFFFu) != 0u) << 2)
                | ((unsigned int)((m.y >> 16) != 0u) << 3);
        }
        unsigned long long b0 = __ballot((nib & 1u) != 0u);
        unsigned long long b1 = __ballot((nib & 2u) != 0u);
        unsigned long long b2 = __ballot((nib & 4u) != 0u);
        unsigned long long b3 = __ballot((nib & 8u) != 0u);
        if (lane < 8) {
            int j = lane >> 1;
            unsigned long long bb = j == 0 ? b0 : j == 1 ? b1 : j == 2 ? b2 : b3;
            lds[xl][lane] = (lane & 1) ? (unsigned int)(bb >> 32) : (unsigned int)bb;
        }
    }
    __syncthreads();
    int widx = (t & 3) * 2 + (t >> 7);
    int bitpos = (t >> 2) & 31;
    unsigned int w = 0u;
    #pragma unroll
    for (int xl = 0; xl < 32; xl++)
        w |= ((lds[xl][widx] >> bitpos) & 1u) << xl;
    maskT[((size_t)bh * 256 + t) * 128 + (x0 >> 5)] = w;
}

// ---------------- S1 = scale * kq (256x32) @ xkT (32x4096), FULL batch ----------------
// grid: (64 xtiles, 4 ktiles, 32 bh)
__global__ __launch_bounds__(256) void s1_kernel(
    const float* __restrict__ kq, const float* __restrict__ xkT, float* __restrict__ S)
{
    __shared__ __align__(16) float Aq[32][68];
    __shared__ __align__(16) float Bs[32][64];
    size_t bhg = (size_t)blockIdx.z;
    int k0 = blockIdx.y * 64;
    int x0 = blockIdx.x * 64;
    int id = threadIdx.x;
    {
        int c4 = (id & 7) * 4;
        #pragma unroll
        for (int rep = 0; rep < 2; rep++) {
            int r = (id >> 3) + rep * 32;
            float4 a = *(const float4*)&kq[(bhg * 256 + k0 + r) * 32 + c4];
            Aq[c4 + 0][r] = a.x; Aq[c4 + 1][r] = a.y;
            Aq[c4 + 2][r] = a.z; Aq[c4 + 3][r] = a.w;
        }
    }
    {
        int c = (id & 15) * 4;
        #pragma unroll
        for (int rep = 0; rep < 2; rep++) {
            int r = (id >> 4) + rep * 16;
            *(float4*)&Bs[r][c] = *(const float4*)&xkT[(bhg * 32 + r) * 4096 + x0 + c];
        }
    }
    __syncthreads();
    int tm = id >> 4, tn = id & 15;
    float acc[4][4] = {};
    #pragma unroll
    for (int dd = 0; dd < 32; dd++) {
        float4 a = *(const float4*)&Aq[dd][tm * 4];
        float4 b = *(const float4*)&Bs[dd][tn * 4];
        float av[4] = {a.x, a.y, a.z, a.w};
        float bv[4] = {b.x, b.y, b.z, b.w};
        #pragma unroll
        for (int i = 0; i < 4; i++)
            #pragma unroll
            for (int j = 0; j < 4; j++)
                acc[i][j] = fmaf(av[i], bv[j], acc[i][j]);
    }
    #pragma unroll
    for (int i = 0; i < 4; i++) {
        float4 o;
        o.x = acc[i][0] * SCALE; o.y = acc[i][1] * SCALE;
        o.z = acc[i][2] * SCALE; o.w = acc[i][3] * SCALE;
        *(float4*)&S[(bhg * 256 + k0 + tm * 4 + i) * 4096 + x0 + tn * 4] = o;
    }
}

// ---------------- path-1: orientation argmax + row stats, FULL batch ----------------
// grid: 8192 blocks (b:2b | k:8b | h:3b), 256 threads
__global__ __launch_bounds__(256) void p1_softmax_kernel(
    const float* __restrict__ S,
    const int* __restrict__ rd, const int* __restrict__ polar,
    const unsigned int* __restrict__ maskT,
    const void* __restrict__ dis_emb, const void* __restrict__ polar_emb,
    int* __restrict__ mori, float2* __restrict__ stats,
    const int* __restrict__ flags)
{
    int idx = blockIdx.x;
    int b = idx >> 11;
    int k = (idx >> 3) & 255;
    int h = idx & 7;
    int bh = b * 8 + h;
    int bhk = bh * 256 + k;
    int t = threadIdx.x;
    int bf = flags[1];
    __shared__ float disc[66];
    __shared__ float pem[8];
    __shared__ float osum[8];
    __shared__ float red[8];
    __shared__ int mo_s;
    if (t < 66) disc[t] = bf ? b2f(((const unsigned short*)dis_emb)[t * 8 + h])
                             : ((const float*)dis_emb)[t * 8 + h];
    if (t < 8) {
        pem[t] = bf ? b2f(((const unsigned short*)polar_emb)[t])
                    : ((const float*)polar_emb)[t];
        osum[t] = 0.f;
    }
    __syncthreads();

    const float* srow = &S[(size_t)bhk * 4096];
    const int* prow = &polar[((size_t)b * 256 + k) * 4096];
    const int* rrow = &rd[((size_t)b * 256 + k) * 4096];

    float s[16]; int po[16];
    float loc[8] = {0.f, 0.f, 0.f, 0.f, 0.f, 0.f, 0.f, 0.f};
    #pragma unroll
    for (int i = 0; i < 16; i++) {
        int x = t + i * 256;
        s[i] = srow[x];
        int p = prow[x];
        p = p < 0 ? 0 : (p > 7 ? 7 : p);
        po[i] = p;
        float a = fabsf(s[i]);
        #pragma unroll
        for (int o = 0; o < 8; o++) loc[o] += (p == o) ? a : 0.f;
    }
    #pragma unroll
    for (int o = 0; o < 8; o++) {
        float v = loc[o];
        #pragma unroll
        for (int m = 32; m; m >>= 1) v += __shfl_xor(v, m);
        if ((t & 63) == 0) atomicAdd(&osum[o], v);
    }
    __syncthreads();
    if (t == 0) {
        float best = osum[0]; int bi = 0;
        #pragma unroll
        for (int o = 1; o < 8; o++) if (osum[o] > best) { best = osum[o]; bi = o; }
        mo_s = bi;
        mori[bhk] = bi;
    }
    __syncthreads();
    int mo = mo_s;
    const unsigned int* mrow = &maskT[(size_t)bhk * 128];
    float mx = -3.4e38f;
    #pragma unroll
    for (int i = 0; i < 16; i++) {
        int x = t + i * 256;
        float bias = disc[rrow[x]] + pem[(po[i] - mo + 8) & 7];
        unsigned int w = mrow[x >> 5];
        float l = (((w >> (x & 31)) & 1u) ? -1e6f : s[i]) + bias;
        s[i] = l;
        mx = fmaxf(mx, l);
    }
    #pragma unroll
    for (int m = 32; m; m >>= 1) mx = fmaxf(mx, __shfl_xor(mx, m));
    if ((t & 63) == 0) red[t >> 6] = mx;
    __syncthreads();
    mx = fmaxf(fmaxf(red[0], red[1]), fmaxf(red[2], red[3]));
    float sum = 0.f;
    #pragma unroll
    for (int i = 0; i < 16; i++) { sum += __expf(s[i] - mx); }
    #pragma unroll
    for (int m = 32; m; m >>= 1) sum += __shfl_xor(sum, m);
    if ((t & 63) == 0) red[4 + (t >> 6)] = sum;
    __syncthreads();
    sum = red[4] + red[5] + red[6] + red[7];
    if (t == 0) stats[bhk] = make_float2(mx, 1.f / sum);
}

// ---------------- av1: (bias+exp fused) A @ xv -> k_att, FULL batch ----
// grid: (16 xs, 4 ktiles, 32 bh)
__global__ __launch_bounds__(256) void av1_kernel(
    const float* __restrict__ S, const float* __restrict__ xv, float* __restrict__ k_att,
    const int* __restrict__ rd, const int* __restrict__ polar,
    const unsigned int* __restrict__ maskT,
    const void* __restrict__ dis_emb, const void* __restrict__ polar_emb,
    const int* __restrict__ mori, const float2* __restrict__ stats,
    const int* __restrict__ flags)
{
    __shared__ __align__(16) float At[64][68];
    __shared__ __align__(16) float Vt[64][32];
    __shared__ float disc[66];
    __shared__ float pem[8];
    __shared__ int mo_l[64];
    __shared__ float mx_l[64];
    __shared__ float inv_l[64];
    int bhg = blockIdx.z, b = bhg >> 3, h = bhg & 7;
    int k0 = blockIdx.y * 64;
    int xs = blockIdx.x;
    int id = threadIdx.x;
    int bf = flags[1];
    if (id < 66) disc[id] = bf ? b2f(((const unsigned short*)dis_emb)[id * 8 + h])
                               : ((const float*)dis_emb)[id * 8 + h];
    if (id < 8) pem[id] = bf ? b2f(((const unsigned short*)polar_emb)[id])
                             : ((const float*)polar_emb)[id];
    if (id < 64) {
        mo_l[id] = mori[(size_t)bhg * 256 + k0 + id];
        float2 st = stats[(size_t)bhg * 256 + k0 + id];
        mx_l[id] = st.x; inv_l[id] = st.y;
    }
    __syncthreads();
    int r = id >> 2, p = id & 3;
    float acc[8] = {};
    for (int c8 = 0; c8 < 4; c8++) {
        int xc = xs * 256 + c8 * 64;
        if (c8) __syncthreads();
        {
            int c = (id & 15) * 4;
            #pragma unroll
            for (int rep = 0; rep < 4; rep++) {
                int rr = (id >> 4) + rep * 16;
                int kg = k0 + rr;
                float4 s4 = *(const float4*)&S[((size_t)bhg * 256 + kg) * 4096 + xc + c];
                size_t rib = ((size_t)b * 256 + kg) * 4096 + xc + c;
                int4 r4 = *(const int4*)&rd[rib];
                int4 p4 = *(const int4*)&polar[rib];
                unsigned int mw = maskT[((size_t)bhg * 256 + kg) * 128 + ((xc + c) >> 5)];
                int mo = mo_l[rr];
                float mx = mx_l[rr];
                float sv[4] = {s4.x, s4.y, s4.z, s4.w};
                int rv[4] = {r4.x, r4.y, r4.z, r4.w};
                int pv[4] = {p4.x, p4.y, p4.z, p4.w};
                float e[4];
                #pragma unroll
                for (int j = 0; j < 4; j++) {
                    int pp = pv[j];
                    pp = pp < 0 ? 0 : (pp > 7 ? 7 : pp);
                    float bias = disc[rv[j]] + pem[(pp - mo + 8) & 7];
                    float l = (((mw >> ((xc + c + j) & 31)) & 1u) ? -1e6f : sv[j]) + bias;
                    e[j] = __expf(l - mx);
                }
                *(float4*)&At[rr][c] = make_float4(e[0], e[1], e[2], e[3]);
            }
        }
        {
            int c = (id & 7) * 4;
            #pragma unroll
            for (int rep = 0; rep < 2; rep++) {
                int rr = (id >> 3) + rep * 32;
                *(float4*)&Vt[rr][c] = *(const float4*)&xv[((size_t)bhg * 4096 + xc + rr) * 32 + c];
            }
        }
        __syncthreads();
        #pragma unroll
        for (int q4 = 0; q4 < 64; q4 += 4) {
            float4 av = *(const float4*)&At[r][q4];
            float aa[4] = {av.x, av.y, av.z, av.w};
            #pragma unroll
            for (int u = 0; u < 4; u++) {
                float4 v0 = *(const float4*)&Vt[q4 + u][p * 8];
                float4 v1 = *(const float4*)&Vt[q4 + u][p * 8 + 4];
                acc[0] = fmaf(aa[u], v0.x, acc[0]);
                acc[1] = fmaf(aa[u], v0.y, acc[1]);
                acc[2] = fmaf(aa[u], v0.z, acc[2]);
                acc[3] = fmaf(aa[u], v0.w, acc[3]);
                acc[4] = fmaf(aa[u], v1.x, acc[4]);
                acc[5] = fmaf(aa[u], v1.y, acc[5]);
                acc[6] = fmaf(aa[u], v1.z, acc[6]);
                acc[7] = fmaf(aa[u], v1.w, acc[7]);
            }
        }
    }
    float inv = inv_l[r];
    float* dst = &k_att[((size_t)b * 256 + k0 + r) * 256 + h * 32 + p * 8];
    #pragma unroll
    for (int j = 0; j < 8; j++) atomicAdd(&dst[j], acc[j] * inv);
}

// ---------------- fa2: kc=32 chunks, transposed P tile, FULL batch ----
// grid: (64 xtiles, 32 bh)
__global__ __launch_bounds__(256) void fa2_kernel(
    const float* __restrict__ kk, const float* __restrict__ xqT, const float* __restrict__ kv,
    const int* __restrict__ rd, const int* __restrict__ polar,
    const unsigned int* __restrict__ maskT,
    const void* __restrict__ dis_emb, const void* __restrict__ polar_emb,
    const int* __restrict__ mori, const int* __restrict__ flags,
    float* __restrict__ x_att)
{
    __shared__ __align__(16) float Aq[32][34];
    __shared__ __align__(16) float Bs[32][64];
    __shared__ __align__(16) float At2[64][34];
    __shared__ __align__(16) float Vt[32][32];
    __shared__ float disc[66];
    __shared__ float pem[8];
    __shared__ int mo_l[256];
    int bhg = blockIdx.y, b = bhg >> 3, h = bhg & 7;
    int x0 = blockIdx.x * 64;
    int id = threadIdx.x;
    int bf = flags[1];
    if (id < 66) disc[id] = bf ? b2f(((const unsigned short*)dis_emb)[id * 8 + h])
                               : ((const float*)dis_emb)[id * 8 + h];
    if (id < 8) pem[id] = bf ? b2f(((const unsigned short*)polar_emb)[id])
                             : ((const float*)polar_emb)[id];
    mo_l[id] = mori[(size_t)bhg * 256 + id];
    {
        int c = (id & 15) * 4;
        #pragma unroll
        for (int rep = 0; rep < 2; rep++) {
            int r = (id >> 4) + rep * 16;
            *(float4*)&Bs[r][c] = *(const float4*)&xqT[((size_t)bhg * 32 + r) * 4096 + x0 + c];
        }
    }
    int tm = id >> 4, tn = id & 15;
    int xr = id >> 2, p = id & 3;
    float acc8[8] = {};
    float m = -3.0e38f, l = 0.f;
    for (int kc = 0; kc < 256; kc += 32) {
        __syncthreads();
        {
            int r = id >> 3, c4 = (id & 7) * 4;
            float4 a = *(const float4*)&kk[((size_t)bhg * 256 + kc + r) * 32 + c4];
            Aq[c4 + 0][r] = a.x; Aq[c4 + 1][r] = a.y;
            Aq[c4 + 2][r] = a.z; Aq[c4 + 3][r] = a.w;
            *(float4*)&Vt[r][c4] = *(const float4*)&kv[((size_t)bhg * 256 + kc + r) * 32 + c4];
        }
        __syncthreads();
        float acc[2][4] = {};
        #pragma unroll
        for (int dd = 0; dd < 32; dd++) {
            float2 a2 = *(const float2*)&Aq[dd][tm * 2];
            float4 b4 = *(const float4*)&Bs[dd][tn * 4];
            float bv[4] = {b4.x, b4.y, b4.z, b4.w};
            #pragma unroll
            for (int j = 0; j < 4; j++) {
                acc[0][j] = fmaf(a2.x, bv[j], acc[0][j]);
                acc[1][j] = fmaf(a2.y, bv[j], acc[1][j]);
            }
        }
        int xb = x0 + tn * 4;
        #pragma unroll
        for (int i = 0; i < 2; i++) {
            int kl = tm * 2 + i;
            int k = kc + kl;
            int mo = mo_l[k];
            size_t rib = ((size_t)b * 256 + k) * 4096 + xb;
            int4 r4 = *(const int4*)&rd[rib];
            int4 p4 = *(const int4*)&polar[rib];
            unsigned int mw = maskT[((size_t)bhg * 256 + k) * 128 + (xb >> 5)];
            int rv[4] = {r4.x, r4.y, r4.z, r4.w};
            int pv[4] = {p4.x, p4.y, p4.z, p4.w};
            #pragma unroll
            for (int j = 0; j < 4; j++) {
                int pp = pv[j];
                pp = pp < 0 ? 0 : (pp > 7 ? 7 : pp);
                float bias = disc[rv[j]] + pem[(pp - mo + 8) & 7];
                float s = acc[i][j] * SCALE;
                At2[tn * 4 + j][kl] =
                    (((mw >> ((xb + j) & 31)) & 1u) ? -1e9f : s) + bias;
            }
        }
        __syncthreads();
        float mc = -3.0e38f;
        #pragma unroll
        for (int q4 = 0; q4 < 32; q4 += 4) {
            float4 v = *(const float4*)&At2[xr][q4];
            mc = fmaxf(mc, fmaxf(fmaxf(v.x, v.y), fmaxf(v.z, v.w)));
        }
        float mn = fmaxf(m, mc);
        float f = __expf(m - mn);
        m = mn;
        l *= f;
        #pragma unroll
        for (int j = 0; j < 8; j++) acc8[j] *= f;
        #pragma unroll
        for (int q4 = 0; q4 < 32; q4 += 4) {
            float4 lv = *(const float4*)&At2[xr][q4];
            float le[4] = {lv.x, lv.y, lv.z, lv.w};
            #pragma unroll
            for (int u = 0; u < 4; u++) {
                float e = __expf(le[u] - m);
                l += e;
                float4 v0 = *(const float4*)&Vt[q4 + u][p * 8];
                float4 v1 = *(const float4*)&Vt[q4 + u][p * 8 + 4];
                acc8[0] = fmaf(e, v0.x, acc8[0]);
                acc8[1] = fmaf(e, v0.y, acc8[1]);
                acc8[2] = fmaf(e, v0.z, acc8[2]);
                acc8[3] = fmaf(e, v0.w, acc8[3]);
                acc8[4] = fmaf(e, v1.x, acc8[4]);
                acc8[5] = fmaf(e, v1.y, acc8[5]);
                acc8[6] = fmaf(e, v1.z, acc8[6]);
                acc8[7] = fmaf(e, v1.w, acc8[7]);
            }
        }
    }
    float inv = 1.f / l;
    float* dst = &x_att[((size_t)b * 4096 + x0 + xr) * 256 + h * 32 + p * 8];
    *(float4*)&dst[0] = make_float4(acc8[0] * inv, acc8[1] * inv, acc8[2] * inv, acc8[3] * inv);
    *(float4*)&dst[4] = make_float4(acc8[4] * inv, acc8[5] * inv, acc8[6] * inv, acc8[7] * inv);
}

// ---------------- final projection ----------------
__global__ __launch_bounds__(256) void proj_kernel(
    const float* __restrict__ A, const void* __restrict__ W, const void* __restrict__ bias,
    float* __restrict__ out, const int* __restrict__ flags)
{
    __shared__ __align__(16) float As[16][68];
    __shared__ __align__(16) float Bs[16][64];
    int bf = flags[1];
    const float* W32 = (const float*)W;
    const unsigned short* W16 = (const unsigned short*)W;
    int m0 = blockIdx.x * 64, n0 = blockIdx.y * 64;
    int id = threadIdx.x, tm = id >> 4, tn = id & 15;
    float acc[4][4] = {};
    for (int k0 = 0; k0 < 256; k0 += 16) {
        int rr = id >> 2, ck = (id & 3) * 4;
        int rk = id >> 4, cn = (id & 15) * 4;
        {
            float4 a4 = *(const float4*)&A[(size_t)(m0 + rr) * 256 + k0 + ck];
            As[ck + 0][rr] = a4.x; As[ck + 1][rr] = a4.y;
            As[ck + 2][rr] = a4.z; As[ck + 3][rr] = a4.w;
        }
        if (bf) {
            uint2 w2 = *(const uint2*)&W16[(size_t)(k0 + rk) * 256 + n0 + cn];
            Bs[rk][cn + 0] = b2f(w2.x & 0xFFFFu); Bs[rk][cn + 1] = b2f(w2.x >> 16);
            Bs[rk][cn + 2] = b2f(w2.y & 0xFFFFu); Bs[rk][cn + 3] = b2f(w2.y >> 16);
        } else {
            *(float4*)&Bs[rk][cn] = *(const float4*)&W32[(size_t)(k0 + rk) * 256 + n0 + cn];
        }
        __syncthreads();
        #pragma unroll
        for (int kk = 0; kk < 16; kk++) {
            float4 a = *(const float4*)&As[kk][tm * 4];
            float4 b = *(const float4*)&Bs[kk][tn * 4];
            float av[4] = {a.x, a.y, a.z, a.w};
            float bv[4] = {b.x, b.y, b.z, b.w};
            #pragma unroll
            for (int i = 0; i < 4; i++)
                #pragma unroll
                for (int j = 0; j < 4; j++)
                    acc[i][j] = fmaf(av[i], bv[j], acc[i][j]);
        }
        __syncthreads();
    }
    #pragma unroll
    for (int i = 0; i < 4; i++) {
        int col = n0 + tn * 4;
        float b0 = bf ? b2f(((const unsigned short*)bias)[col + 0]) : ((const float*)bias)[col + 0];
        float b1 = bf ? b2f(((const unsigned short*)bias)[col + 1]) : ((const float*)bias)[col + 1];
        float b2v = bf ? b2f(((const unsigned short*)bias)[col + 2]) : ((const float*)bias)[col + 2];
        float b3 = bf ? b2f(((const unsigned short*)bias)[col + 3]) : ((const float*)bias)[col + 3];
        float4 o = make_float4(acc[i][0] + b0, acc[i][1] + b1, acc[i][2] + b2v, acc[i][3] + b3);
        *(float4*)&out[(size_t)(m0 + tm * 4 + i) * 256 + col] = o;
    }
}

extern "C" void kernel_launch(void* const* d_in, const int* in_sizes, int n_in,
                              void* d_out, int out_size, void* d_ws, size_t ws_size,
                              hipStream_t stream) {
    (void)in_sizes; (void)n_in; (void)out_size; (void)ws_size;
    const void* x         = d_in[0];
    const void* kern      = d_in[1];
    const int*  rd        = (const int*)d_in[2];
    const int*  polar     = (const int*)d_in[3];
    const void* amask     = d_in[4];
    const void* w_qkv     = d_in[5];
    const void* w_proj    = d_in[6];
    const void* b_proj    = d_in[7];
    const void* polar_emb = d_in[8];
    const void* dis_emb   = d_in[9];
    float* out = (float*)d_out;

    float* ws = (float*)d_ws;
    float* S     = ws + OFF_S;
    float* xqT   = ws + OFF_XQT;
    float* xv    = ws + OFF_XV;
    float* xkT   = ws + OFF_XKT;
    float* kq    = ws + OFF_KQ;
    float* kkM   = ws + OFF_KK;
    float* kvM   = ws + OFF_KV;
    float* k_att = ws + OFF_KATT;
    float* x_att = ws + OFF_XATT;
    unsigned int* maskT = (unsigned int*)(ws + OFF_MT);
    int* mori  = (int*)(ws + OFF_MORI);
    float2* stats = (float2*)(ws + OFF_STAT);
    int* flags = (int*)(ws + OFF_FLAG);

    detect_kernel<<<2, 256, 0, stream>>>((const unsigned int*)amask, (const unsigned int*)x, flags);
    qkv128_kernel<<<dim3(128, 12), 256, 0, stream>>>(x, w_qkv, xqT, xkT, xv, flags);
    qkv_kernel<<<dim3(16, 12), 256, 0, stream>>>(kern, w_qkv, kq, kkM, kvM, flags);
    maskpack_kernel<<<4096, 256, 0, stream>>>(amask, maskT, flags);
    hipMemsetAsync(k_att, 0, 262144 * sizeof(float), stream);

    // FULL-batch pipeline (no halves)
    s1_kernel<<<dim3(64, 4, 32), 256, 0, stream>>>(kq, xkT, S);
    p1_softmax_kernel<<<8192, 256, 0, stream>>>(S, rd, polar, maskT, dis_emb, polar_emb,
                                                mori, stats, flags);
    av1_kernel<<<dim3(16, 4, 32), 256, 0, stream>>>(S, xv, k_att, rd, polar, maskT,
                                                    dis_emb, polar_emb, mori, stats, flags);
    fa2_kernel<<<dim3(64, 32), 256, 0, stream>>>(kkM, xqT, kvM, rd, polar, maskT,
                                                 dis_emb, polar_emb, mori, flags, x_att);

    proj_kernel<<<dim3(256, 4), 256, 0, stream>>>(x_att, w_proj, b_proj, out, flags);
    proj_kernel<<<dim3(16, 4), 256, 0, stream>>>(k_att, w_proj, b_proj, out + 4194304, flags);
}